// Round 2
// baseline (1374.354 us; speedup 1.0000x reference)
//
#include <hip/hip_runtime.h>
#include <hip/hip_bf16.h>
#include <math.h>

#define NB 4096
#define HD 256
#define NP 128
#define NV 2000
#define NATOMS 32768
#define NRES 262144

__device__ __forceinline__ int lower_bound_i(const int* __restrict__ arr, int n, int val) {
  int lo = 0, hi = n;
  while (lo < hi) { int mid = (lo + hi) >> 1; if (arr[mid] < val) lo = mid + 1; else hi = mid; }
  return lo;
}

// Per-batch atom segment sums: node_hiddens (B,H), center_pos (B,3)
__global__ void k_atoms(const float* __restrict__ hctx, const float* __restrict__ pos,
                        const int* __restrict__ ab, float* __restrict__ nh,
                        float* __restrict__ center) {
  int b = blockIdx.x, t = threadIdx.x;
  int s = lower_bound_i(ab, NATOMS, b);
  int e = lower_bound_i(ab, NATOMS, b + 1);
  float acc = 0.f;
  for (int a = s; a < e; ++a) acc += hctx[(size_t)a * HD + t];
  nh[(size_t)b * HD + t] = acc;
  if (t < 3) {
    float ps = 0.f;
    for (int a = s; a < e; ++a) ps += pos[a * 3 + t];
    center[b * 3 + t] = ps / fmaxf((float)(e - s), 1.0f);
  }
}

// Per-batch residue masked segment sum: residue_emb (B,H)
__global__ void k_res(const float* __restrict__ hres, const float* __restrict__ rpos,
                      const int* __restrict__ rb, const float* __restrict__ center,
                      float* __restrict__ re) {
  int b = blockIdx.x, t = threadIdx.x;
  int s = lower_bound_i(rb, NRES, b);
  int e = lower_bound_i(rb, NRES, b + 1);
  float c0 = center[b * 3], c1 = center[b * 3 + 1], c2 = center[b * 3 + 2];
  float acc = 0.f;
  for (int r = s; r < e; ++r) {
    float dx = rpos[(size_t)r * 9 + 3] - c0;
    float dy = rpos[(size_t)r * 9 + 4] - c1;
    float dz = rpos[(size_t)r * 9 + 5] - c2;
    if (dx * dx + dy * dy + dz * dz < 36.0f)  // dist < 6
      acc += hres[(size_t)r * HD + t];
  }
  re[(size_t)b * HD + t] = acc;
}

// sum_proto -> inv_sp[p] = 1/(sum+1)
__global__ void k_sumproto(const float* __restrict__ pcnt, float* __restrict__ inv_sp) {
  int p = blockIdx.x, t = threadIdx.x;
  __shared__ float red[256];
  float s = 0.f;
  for (int v = t; v < NV; v += 256) s += pcnt[(size_t)p * NV + v];
  red[t] = s; __syncthreads();
  for (int off = 128; off > 0; off >>= 1) { if (t < off) red[t] += red[t + off]; __syncthreads(); }
  if (t == 0) inv_sp[p] = 1.0f / (red[0] + 1.0f);
}

// wl[v] = log((1+P)/(1+sum_motif[v])) + 1
__global__ void k_wl(const float* __restrict__ pcnt, float* __restrict__ wl) {
  int v = blockIdx.x * blockDim.x + threadIdx.x;
  if (v >= NV) return;
  float sm = 0.f;
  for (int p = 0; p < NP; ++p) sm += (pcnt[(size_t)p * NV + v] > 0.f) ? 1.f : 0.f;
  wl[v] = logf((1.0f + NP) / (1.0f + sm)) + 1.0f;
}

// bemb[p] = inv_sp[p] * sum_v pcnt[p,v]*wl[v]*emb[v]
__global__ void k_bemb(const float* __restrict__ pcnt, const float* __restrict__ wl,
                       const float* __restrict__ inv_sp, const float* __restrict__ emb,
                       float* __restrict__ bemb) {
  int p = blockIdx.x, t = threadIdx.x;
  __shared__ float cw[NV];
  for (int v = t; v < NV; v += 256) cw[v] = pcnt[(size_t)p * NV + v] * wl[v];
  __syncthreads();
  float acc = 0.f;
  for (int v = 0; v < NV; ++v) acc += cw[v] * emb[(size_t)v * HD + t];
  bemb[p * HD + t] = acc * inv_sp[p];
}

// l2-normalized prototypes, stored transposed: pnT[h*P+p]
__global__ void k_proton(const float* __restrict__ proto, float* __restrict__ pnT) {
  int p = blockIdx.x, t = threadIdx.x;
  __shared__ float red[256];
  float x = proto[p * HD + t];
  red[t] = x * x; __syncthreads();
  for (int off = 128; off > 0; off >>= 1) { if (t < off) red[t] += red[t + off]; __syncthreads(); }
  float inv = 1.0f / fmaxf(sqrtf(red[0]), 1e-12f);
  pnT[t * NP + p] = x * inv;
}

// cos = l2norm(re[b]) . pn[p], then top-4 indices (jax tie-break: lower index)
__global__ void k_costopk(const float* __restrict__ re, const float* __restrict__ pnT,
                          int* __restrict__ knn) {
  int b = blockIdx.x, t = threadIdx.x;  // 128 threads
  __shared__ float sre[HD];
  __shared__ float red[128];
  __shared__ float c[NP];
  __shared__ float rv[128];
  __shared__ int   ri[128];
  float x0 = re[(size_t)b * HD + t], x1 = re[(size_t)b * HD + 128 + t];
  sre[t] = x0; sre[128 + t] = x1;
  red[t] = x0 * x0 + x1 * x1;
  __syncthreads();
  for (int off = 64; off > 0; off >>= 1) { if (t < off) red[t] += red[t + off]; __syncthreads(); }
  float invn = 1.0f / fmaxf(sqrtf(red[0]), 1e-12f);
  float d = 0.f;
  for (int h = 0; h < HD; ++h) d += sre[h] * pnT[h * NP + t];
  c[t] = d * invn;
  __syncthreads();
  for (int k = 0; k < 4; ++k) {
    rv[t] = c[t]; ri[t] = t; __syncthreads();
    for (int off = 64; off > 0; off >>= 1) {
      if (t < off) {
        float ov = rv[t + off]; int oi = ri[t + off];
        if (ov > rv[t] || (ov == rv[t] && oi < ri[t])) { rv[t] = ov; ri[t] = oi; }
      }
      __syncthreads();
    }
    int best = ri[0];
    if (t == 0) knn[b * 4 + k] = best;
    if (t == best) c[t] = -INFINITY;
    __syncthreads();
  }
}

// hin[p] = sum_{b: p in knn(b)} re[b] + bemb[p]
__global__ void k_paccum(const float* __restrict__ re, const int* __restrict__ knn,
                         const float* __restrict__ bemb, float* __restrict__ hin) {
  int p = blockIdx.x, t = threadIdx.x;
  float acc = 0.f;
  for (int b = 0; b < NB; ++b) {
    int4 kn = ((const int4*)knn)[b];
    if (kn.x == p || kn.y == p || kn.z == p || kn.w == p) acc += re[(size_t)b * HD + t];
  }
  hin[p * HD + t] = acc + bemb[p * HD + t];
}

// h1p[p] = relu(hin[p] @ gnn_w1)
__global__ void k_h1(const float* __restrict__ hin, const float* __restrict__ w1,
                     float* __restrict__ h1p) {
  int p = blockIdx.x, t = threadIdx.x;
  __shared__ float s[HD];
  s[t] = hin[p * HD + t];
  __syncthreads();
  float acc = 0.f;
  for (int h = 0; h < HD; ++h) acc += s[h] * w1[h * HD + t];
  h1p[p * HD + t] = fmaxf(acc, 0.f);
}

// ro[b] = (sum_{k} h1p[knn[b][k]]) @ gnn_w2   (8 rows per block)
__global__ void k_ro(const int* __restrict__ knn, const float* __restrict__ h1p,
                     const float* __restrict__ w2, float* __restrict__ ro) {
  int b0 = blockIdx.x * 8, t = threadIdx.x;
  __shared__ float s[8][HD];
  for (int i = 0; i < 8; ++i) {
    int4 kn = ((const int4*)knn)[b0 + i];
    s[i][t] = h1p[kn.x * HD + t] + h1p[kn.y * HD + t] + h1p[kn.z * HD + t] + h1p[kn.w * HD + t];
  }
  __syncthreads();
  float acc[8] = {};
  for (int h = 0; h < HD; ++h) {
    float w = w2[h * HD + t];
#pragma unroll
    for (int i = 0; i < 8; ++i) acc[i] += s[i][h] * w;
  }
  for (int i = 0; i < 8; ++i) ro[(size_t)(b0 + i) * HD + t] = acc[i];
}

// U[b] = [0.8*nh[b] | 0.7*emb[wid[b]] | 1.5*ro[b]]
__global__ void k_buildU(const float* __restrict__ nh, const float* __restrict__ emb,
                         const int* __restrict__ wid, const float* __restrict__ ro,
                         float* __restrict__ U) {
  int b = blockIdx.x, t = threadIdx.x;
  U[(size_t)b * 768 + t]       = 0.8f * nh[(size_t)b * HD + t];
  U[(size_t)b * 768 + 256 + t] = 0.7f * emb[(size_t)wid[b] * HD + t];
  U[(size_t)b * 768 + 512 + t] = 1.5f * ro[(size_t)b * HD + t];
}

// embT[h*2001+v] = emb[v*256+h]
__global__ void k_transpose(const float* __restrict__ emb, float* __restrict__ embT) {
  __shared__ float tile[32][33];
  int v0 = blockIdx.x * 32, h0 = blockIdx.y * 32;
  int tx = threadIdx.x % 32, ty = threadIdx.x / 32;  // 8 rows at a time
  for (int r = ty; r < 32; r += 8) {
    int v = v0 + r;
    tile[r][tx] = (v < 2001) ? emb[(size_t)v * HD + h0 + tx] : 0.f;
  }
  __syncthreads();
  for (int r = ty; r < 32; r += 8) {
    int h = h0 + r, v = v0 + tx;
    if (v < 2001) embT[(size_t)h * 2001 + v] = tile[tx][r];
  }
}

// C = A(MxK) @ B(KxN) [+ bias], f32, 64x64 tile, 4x4 micro, BK=32
__global__ __launch_bounds__(256) void k_gemm(const float* __restrict__ A,
                                              const float* __restrict__ Bm,
                                              const float* __restrict__ bias,
                                              float* __restrict__ C,
                                              int M, int N, int K) {
  const int BM = 64, BN = 64, BK = 32;
  __shared__ float As[BK][BM + 4];
  __shared__ float Bs[BK][BN];
  int tid = threadIdx.x;
  int tx = tid % 16, ty = tid / 16;
  int bm = blockIdx.x * BM, bn = blockIdx.y * BN;
  float acc[4][4] = {};
  for (int k0 = 0; k0 < K; k0 += BK) {
    for (int i = tid; i < BM * BK; i += 256) {
      int m = i / BK, k = i % BK;
      As[k][m] = A[(size_t)(bm + m) * K + k0 + k];
    }
    for (int i = tid; i < BK * BN; i += 256) {
      int k = i / BN, n = i % BN;
      int col = bn + n;
      Bs[k][n] = (col < N) ? Bm[(size_t)(k0 + k) * N + col] : 0.f;
    }
    __syncthreads();
#pragma unroll
    for (int k = 0; k < BK; ++k) {
      float a[4], b[4];
#pragma unroll
      for (int i = 0; i < 4; ++i) a[i] = As[k][ty * 4 + i];
#pragma unroll
      for (int j = 0; j < 4; ++j) b[j] = Bs[k][tx * 4 + j];
#pragma unroll
      for (int i = 0; i < 4; ++i)
#pragma unroll
        for (int j = 0; j < 4; ++j) acc[i][j] += a[i] * b[j];
    }
    __syncthreads();
  }
  for (int i = 0; i < 4; ++i) {
    int row = bm + ty * 4 + i;
    for (int j = 0; j < 4; ++j) {
      int col = bn + tx * 4 + j;
      if (col < N) {
        float v = acc[i][j] + (bias ? bias[col] : 0.f);
        C[(size_t)row * N + col] = v;
      }
    }
  }
}

extern "C" void kernel_launch(void* const* d_in, const int* in_sizes, int n_in,
                              void* d_out, int out_size, void* d_ws, size_t ws_size,
                              hipStream_t stream) {
  const float* hctx  = (const float*)d_in[0];
  const float* pos   = (const float*)d_in[1];
  const float* hres  = (const float*)d_in[2];
  const float* rpos  = (const float*)d_in[3];
  const float* emb   = (const float*)d_in[4];
  const float* proto = (const float*)d_in[5];
  const float* pcnt  = (const float*)d_in[6];
  const float* mw    = (const float*)d_in[7];
  const float* mb    = (const float*)d_in[8];
  const float* w1    = (const float*)d_in[9];
  const float* w2    = (const float*)d_in[10];
  const int* wid     = (const int*)d_in[11];
  const int* ab      = (const int*)d_in[12];
  const int* rb      = (const int*)d_in[13];
  float* out = (float*)d_out;

  // workspace layout (floats), all 16B-aligned
  float* ws     = (float*)d_ws;
  float* nh     = ws;                       // NB*HD      = 1048576
  float* center = nh + (size_t)NB * HD;     // NB*4       (uses 3)
  float* re     = center + (size_t)NB * 4;  // NB*HD
  float* inv_sp = re + (size_t)NB * HD;     // NP
  float* wl     = inv_sp + NP;              // NV
  float* bemb   = wl + NV;                  // NP*HD
  float* pnT    = bemb + NP * HD;           // HD*NP
  float* hin    = pnT + NP * HD;            // NP*HD
  float* h1p    = hin + NP * HD;            // NP*HD
  float* ro     = h1p + NP * HD;            // NB*HD
  float* U      = ro + (size_t)NB * HD;     // NB*768
  float* tb     = U + (size_t)NB * 768;     // NB*HD
  float* embT   = tb + (size_t)NB * HD;     // HD*2001
  // round up to 16B alignment for int4 loads of knn
  int*   knn    = (int*)(embT + (((size_t)HD * 2001 + 3) & ~(size_t)3));  // NB*4 ints

  k_atoms<<<NB, 256, 0, stream>>>(hctx, pos, ab, nh, center);
  k_res<<<NB, 256, 0, stream>>>(hres, rpos, rb, center, re);
  k_sumproto<<<NP, 256, 0, stream>>>(pcnt, inv_sp);
  k_wl<<<(NV + 255) / 256, 256, 0, stream>>>(pcnt, wl);
  k_bemb<<<NP, 256, 0, stream>>>(pcnt, wl, inv_sp, emb, bemb);
  k_proton<<<NP, 256, 0, stream>>>(proto, pnT);
  k_costopk<<<NB, 128, 0, stream>>>(re, pnT, knn);
  k_paccum<<<NP, 256, 0, stream>>>(re, knn, bemb, hin);
  k_h1<<<NP, 256, 0, stream>>>(hin, w1, h1p);
  k_ro<<<NB / 8, 256, 0, stream>>>(knn, h1p, w2, ro);
  k_buildU<<<NB, 256, 0, stream>>>(nh, emb, wid, ro, U);
  k_transpose<<<dim3(63, 8), 256, 0, stream>>>(emb, embT);
  // t = U @ motif_w + motif_b   (4096x768 @ 768x256)
  k_gemm<<<dim3(NB / 64, 4), 256, 0, stream>>>(U, mw, mb, tb, NB, 256, 768);
  // scores = t @ emb.T          (4096x256 @ 256x2001)
  k_gemm<<<dim3(NB / 64, 32), 256, 0, stream>>>(tb, embT, nullptr, out, NB, 2001, 256);
}

// Round 4
// 845.918 us; speedup vs baseline: 1.6247x; 1.6247x over previous
//
#include <hip/hip_runtime.h>
#include <hip/hip_bf16.h>
#include <math.h>

#define NB 4096
#define HD 256
#define NP 128
#define NV 2000
#define NATOMS 32768
#define NRES 262144
#define VCHUNK 125  // 2000 = 16 * 125

__device__ __forceinline__ int lower_bound_i(const int* __restrict__ arr, int n, int val) {
  int lo = 0, hi = n;
  while (lo < hi) { int mid = (lo + hi) >> 1; if (arr[mid] < val) lo = mid + 1; else hi = mid; }
  return lo;
}

// Per-batch atom segment sums: node_hiddens (B,H), center_pos (B,3)
__global__ void k_atoms(const float* __restrict__ hctx, const float* __restrict__ pos,
                        const int* __restrict__ ab, float* __restrict__ nh,
                        float* __restrict__ center) {
  int b = blockIdx.x, t = threadIdx.x;
  int s = lower_bound_i(ab, NATOMS, b);
  int e = lower_bound_i(ab, NATOMS, b + 1);
  float acc = 0.f;
  for (int a = s; a < e; ++a) acc += hctx[(size_t)a * HD + t];
  nh[(size_t)b * HD + t] = acc;
  if (t < 3) {
    float ps = 0.f;
    for (int a = s; a < e; ++a) ps += pos[a * 3 + t];
    center[b * 3 + t] = ps / fmaxf((float)(e - s), 1.0f);
  }
}

// Per-batch residue masked segment sum: residue_emb (B,H)
__global__ void k_res(const float* __restrict__ hres, const float* __restrict__ rpos,
                      const int* __restrict__ rb, const float* __restrict__ center,
                      float* __restrict__ re) {
  int b = blockIdx.x, t = threadIdx.x;
  int s = lower_bound_i(rb, NRES, b);
  int e = lower_bound_i(rb, NRES, b + 1);
  float c0 = center[b * 3], c1 = center[b * 3 + 1], c2 = center[b * 3 + 2];
  float acc = 0.f;
  for (int r = s; r < e; ++r) {
    float dx = rpos[(size_t)r * 9 + 3] - c0;
    float dy = rpos[(size_t)r * 9 + 4] - c1;
    float dz = rpos[(size_t)r * 9 + 5] - c2;
    if (dx * dx + dy * dy + dz * dz < 36.0f)  // dist < 6
      acc += hres[(size_t)r * HD + t];
  }
  re[(size_t)b * HD + t] = acc;
}

// sum_proto -> inv_sp[p] = 1/(sum+1)
__global__ void k_sumproto(const float* __restrict__ pcnt, float* __restrict__ inv_sp) {
  int p = blockIdx.x, t = threadIdx.x;
  __shared__ float red[256];
  float s = 0.f;
  for (int v = t; v < NV; v += 256) s += pcnt[(size_t)p * NV + v];
  red[t] = s; __syncthreads();
  for (int off = 128; off > 0; off >>= 1) { if (t < off) red[t] += red[t + off]; __syncthreads(); }
  if (t == 0) inv_sp[p] = 1.0f / (red[0] + 1.0f);
}

// wl[v] = log((1+P)/(1+sum_motif[v])) + 1
__global__ void k_wl(const float* __restrict__ pcnt, float* __restrict__ wl) {
  int v = blockIdx.x * blockDim.x + threadIdx.x;
  if (v >= NV) return;
  float sm = 0.f;
  for (int p = 0; p < NP; ++p) sm += (pcnt[(size_t)p * NV + v] > 0.f) ? 1.f : 0.f;
  wl[v] = logf((1.0f + NP) / (1.0f + sm)) + 1.0f;
}

// hin[p] += inv_sp[p] * sum_{v in chunk} pcnt[p,v]*wl[v]*emb[v]   (split-K, atomic)
__global__ void k_bemb2(const float* __restrict__ pcnt, const float* __restrict__ wl,
                        const float* __restrict__ inv_sp, const float* __restrict__ emb,
                        float* __restrict__ hin) {
  int p = blockIdx.x, c = blockIdx.y, t = threadIdx.x;
  __shared__ float cw[VCHUNK];
  int v0 = c * VCHUNK;
  float isp = inv_sp[p];
  for (int v = t; v < VCHUNK; v += 256) cw[v] = pcnt[(size_t)p * NV + v0 + v] * wl[v0 + v] * isp;
  __syncthreads();
  float acc = 0.f;
#pragma unroll 5
  for (int v = 0; v < VCHUNK; ++v) acc += cw[v] * emb[(size_t)(v0 + v) * HD + t];
  atomicAdd(&hin[p * HD + t], acc);
}

// l2-normalized prototypes, stored transposed: pnT[h*P+p]
__global__ void k_proton(const float* __restrict__ proto, float* __restrict__ pnT) {
  int p = blockIdx.x, t = threadIdx.x;
  __shared__ float red[256];
  float x = proto[p * HD + t];
  red[t] = x * x; __syncthreads();
  for (int off = 128; off > 0; off >>= 1) { if (t < off) red[t] += red[t + off]; __syncthreads(); }
  float inv = 1.0f / fmaxf(sqrtf(red[0]), 1e-12f);
  pnT[t * NP + p] = x * inv;
}

// cos = l2norm(re[b]) . pn[p]; top-4 -> knn; then scatter re[b] into hin rows (atomic)
__global__ void k_costopk(const float* __restrict__ re, const float* __restrict__ pnT,
                          int* __restrict__ knn, float* __restrict__ hin) {
  int b = blockIdx.x, t = threadIdx.x;  // 128 threads
  __shared__ float sre[HD];
  __shared__ float red[128];
  __shared__ float c[NP];
  __shared__ float rv[128];
  __shared__ int   ri[128];
  __shared__ int   kk[4];
  float x0 = re[(size_t)b * HD + t], x1 = re[(size_t)b * HD + 128 + t];
  sre[t] = x0; sre[128 + t] = x1;
  red[t] = x0 * x0 + x1 * x1;
  __syncthreads();
  for (int off = 64; off > 0; off >>= 1) { if (t < off) red[t] += red[t + off]; __syncthreads(); }
  float invn = 1.0f / fmaxf(sqrtf(red[0]), 1e-12f);
  float d = 0.f;
  for (int h = 0; h < HD; ++h) d += sre[h] * pnT[h * NP + t];
  c[t] = d * invn;
  __syncthreads();
  for (int k = 0; k < 4; ++k) {
    rv[t] = c[t]; ri[t] = t; __syncthreads();
    for (int off = 64; off > 0; off >>= 1) {
      if (t < off) {
        float ov = rv[t + off]; int oi = ri[t + off];
        if (ov > rv[t] || (ov == rv[t] && oi < ri[t])) { rv[t] = ov; ri[t] = oi; }
      }
      __syncthreads();
    }
    int best = ri[0];
    if (t == 0) { knn[b * 4 + k] = best; kk[k] = best; }
    if (t == best) c[t] = -INFINITY;
    __syncthreads();
  }
  // scatter: hin[p] += re[b] for each of the 4 knn prototypes
#pragma unroll
  for (int k = 0; k < 4; ++k) {
    int p = kk[k];
    atomicAdd(&hin[p * HD + t], sre[t]);
    atomicAdd(&hin[p * HD + 128 + t], sre[128 + t]);
  }
}

// h1p[p] = relu(hin[p] @ gnn_w1)
__global__ void k_h1(const float* __restrict__ hin, const float* __restrict__ w1,
                     float* __restrict__ h1p) {
  int p = blockIdx.x, t = threadIdx.x;
  __shared__ float s[HD];
  s[t] = hin[p * HD + t];
  __syncthreads();
  float acc = 0.f;
  for (int h = 0; h < HD; ++h) acc += s[h] * w1[h * HD + t];
  h1p[p * HD + t] = fmaxf(acc, 0.f);
}

// ro[b] = (sum_{k} h1p[knn[b][k]]) @ gnn_w2   (8 rows per block)
__global__ void k_ro(const int* __restrict__ knn, const float* __restrict__ h1p,
                     const float* __restrict__ w2, float* __restrict__ ro) {
  int b0 = blockIdx.x * 8, t = threadIdx.x;
  __shared__ float s[8][HD];
  for (int i = 0; i < 8; ++i) {
    int4 kn = ((const int4*)knn)[b0 + i];
    s[i][t] = h1p[kn.x * HD + t] + h1p[kn.y * HD + t] + h1p[kn.z * HD + t] + h1p[kn.w * HD + t];
  }
  __syncthreads();
  float acc[8] = {};
  for (int h = 0; h < HD; ++h) {
    float w = w2[h * HD + t];
#pragma unroll
    for (int i = 0; i < 8; ++i) acc[i] += s[i][h] * w;
  }
  for (int i = 0; i < 8; ++i) ro[(size_t)(b0 + i) * HD + t] = acc[i];
}

// U[b] = [0.8*nh[b] | 0.7*emb[wid[b]] | 1.5*ro[b]]
__global__ void k_buildU(const float* __restrict__ nh, const float* __restrict__ emb,
                         const int* __restrict__ wid, const float* __restrict__ ro,
                         float* __restrict__ U) {
  int b = blockIdx.x, t = threadIdx.x;
  U[(size_t)b * 768 + t]       = 0.8f * nh[(size_t)b * HD + t];
  U[(size_t)b * 768 + 256 + t] = 0.7f * emb[(size_t)wid[b] * HD + t];
  U[(size_t)b * 768 + 512 + t] = 1.5f * ro[(size_t)b * HD + t];
}

// embT[h*2001+v] = emb[v*256+h]
__global__ void k_transpose(const float* __restrict__ emb, float* __restrict__ embT) {
  __shared__ float tile[32][33];
  int v0 = blockIdx.x * 32, h0 = blockIdx.y * 32;
  int tx = threadIdx.x % 32, ty = threadIdx.x / 32;  // 8 rows at a time
  for (int r = ty; r < 32; r += 8) {
    int v = v0 + r;
    tile[r][tx] = (v < 2001) ? emb[(size_t)v * HD + h0 + tx] : 0.f;
  }
  __syncthreads();
  for (int r = ty; r < 32; r += 8) {
    int h = h0 + r, v = v0 + tx;
    if (v < 2001) embT[(size_t)h * 2001 + v] = tile[tx][r];
  }
}

// C = A(MxK) @ B(KxN) [+ bias], f32, 64x64 tile, 4x4 micro, BK=32
__global__ __launch_bounds__(256) void k_gemm(const float* __restrict__ A,
                                              const float* __restrict__ Bm,
                                              const float* __restrict__ bias,
                                              float* __restrict__ C,
                                              int M, int N, int K) {
  const int BM = 64, BN = 64, BK = 32;
  __shared__ float As[BK][BM + 4];
  __shared__ float Bs[BK][BN];
  int tid = threadIdx.x;
  int tx = tid % 16, ty = tid / 16;
  int bm = blockIdx.x * BM, bn = blockIdx.y * BN;
  float acc[4][4] = {};
  for (int k0 = 0; k0 < K; k0 += BK) {
    for (int i = tid; i < BM * BK; i += 256) {
      int m = i / BK, k = i % BK;
      As[k][m] = A[(size_t)(bm + m) * K + k0 + k];
    }
    for (int i = tid; i < BK * BN; i += 256) {
      int k = i / BN, n = i % BN;
      int col = bn + n;
      Bs[k][n] = (col < N) ? Bm[(size_t)(k0 + k) * N + col] : 0.f;
    }
    __syncthreads();
#pragma unroll
    for (int k = 0; k < BK; ++k) {
      float a[4], b[4];
#pragma unroll
      for (int i = 0; i < 4; ++i) a[i] = As[k][ty * 4 + i];
#pragma unroll
      for (int j = 0; j < 4; ++j) b[j] = Bs[k][tx * 4 + j];
#pragma unroll
      for (int i = 0; i < 4; ++i)
#pragma unroll
        for (int j = 0; j < 4; ++j) acc[i][j] += a[i] * b[j];
    }
    __syncthreads();
  }
  for (int i = 0; i < 4; ++i) {
    int row = bm + ty * 4 + i;
    for (int j = 0; j < 4; ++j) {
      int col = bn + tx * 4 + j;
      if (col < N) {
        float v = acc[i][j] + (bias ? bias[col] : 0.f);
        C[(size_t)row * N + col] = v;
      }
    }
  }
}

extern "C" void kernel_launch(void* const* d_in, const int* in_sizes, int n_in,
                              void* d_out, int out_size, void* d_ws, size_t ws_size,
                              hipStream_t stream) {
  const float* hctx  = (const float*)d_in[0];
  const float* pos   = (const float*)d_in[1];
  const float* hres  = (const float*)d_in[2];
  const float* rpos  = (const float*)d_in[3];
  const float* emb   = (const float*)d_in[4];
  const float* proto = (const float*)d_in[5];
  const float* pcnt  = (const float*)d_in[6];
  const float* mw    = (const float*)d_in[7];
  const float* mb    = (const float*)d_in[8];
  const float* w1    = (const float*)d_in[9];
  const float* w2    = (const float*)d_in[10];
  const int* wid     = (const int*)d_in[11];
  const int* ab      = (const int*)d_in[12];
  const int* rb      = (const int*)d_in[13];
  float* out = (float*)d_out;

  // workspace layout (floats), all 16B-aligned
  float* ws     = (float*)d_ws;
  float* nh     = ws;                       // NB*HD
  float* center = nh + (size_t)NB * HD;     // NB*4 (uses 3)
  float* re     = center + (size_t)NB * 4;  // NB*HD
  float* inv_sp = re + (size_t)NB * HD;     // NP
  float* wl     = inv_sp + NP;              // NV
  float* pnT    = wl + NV;                  // HD*NP
  float* hin    = pnT + NP * HD;            // NP*HD  (zeroed; bemb + knn-scatter accumulate here)
  float* h1p    = hin + NP * HD;            // NP*HD
  float* ro     = h1p + NP * HD;            // NB*HD
  float* U      = ro + (size_t)NB * HD;     // NB*768
  float* tb     = U + (size_t)NB * 768;     // NB*HD
  float* embT   = tb + (size_t)NB * HD;     // HD*2001
  int*   knn    = (int*)(embT + (((size_t)HD * 2001 + 3) & ~(size_t)3));  // NB*4 ints, 16B aligned

  hipMemsetAsync(hin, 0, (size_t)NP * HD * sizeof(float), stream);
  k_atoms<<<NB, 256, 0, stream>>>(hctx, pos, ab, nh, center);
  k_res<<<NB, 256, 0, stream>>>(hres, rpos, rb, center, re);
  k_sumproto<<<NP, 256, 0, stream>>>(pcnt, inv_sp);
  k_wl<<<(NV + 255) / 256, 256, 0, stream>>>(pcnt, wl);
  k_bemb2<<<dim3(NP, 16), 256, 0, stream>>>(pcnt, wl, inv_sp, emb, hin);
  k_proton<<<NP, 256, 0, stream>>>(proto, pnT);
  k_costopk<<<NB, 128, 0, stream>>>(re, pnT, knn, hin);
  k_h1<<<NP, 256, 0, stream>>>(hin, w1, h1p);
  k_ro<<<NB / 8, 256, 0, stream>>>(knn, h1p, w2, ro);
  k_buildU<<<NB, 256, 0, stream>>>(nh, emb, wid, ro, U);
  k_transpose<<<dim3(63, 8), 256, 0, stream>>>(emb, embT);
  // t = U @ motif_w + motif_b   (4096x768 @ 768x256)
  k_gemm<<<dim3(NB / 64, 4), 256, 0, stream>>>(U, mw, mb, tb, NB, 256, 768);
  // scores = t @ emb.T          (4096x256 @ 256x2001)
  k_gemm<<<dim3(NB / 64, 32), 256, 0, stream>>>(tb, embT, nullptr, out, NB, 2001, 256);
}

// Round 6
// 808.242 us; speedup vs baseline: 1.7004x; 1.0466x over previous
//
#include <hip/hip_runtime.h>
#include <hip/hip_bf16.h>
#include <math.h>

#define NB 4096
#define HD 256
#define NP 128
#define NV 2000
#define NATOMS 32768
#define NRES 262144
#define VCHUNK 125  // 2000 = 16 * 125

typedef __attribute__((ext_vector_type(8))) short bf16x8;
typedef __attribute__((ext_vector_type(4))) float f32x4;

__device__ __forceinline__ unsigned short f2bf(float f) {
  unsigned int u = __builtin_bit_cast(unsigned int, f);
  u += 0x7FFFu + ((u >> 16) & 1u);  // RNE
  return (unsigned short)(u >> 16);
}
__device__ __forceinline__ float bf2f(unsigned short h) {
  unsigned int u = ((unsigned int)h) << 16;
  return __builtin_bit_cast(float, u);
}

__device__ __forceinline__ int lower_bound_i(const int* __restrict__ arr, int n, int val) {
  int lo = 0, hi = n;
  while (lo < hi) { int mid = (lo + hi) >> 1; if (arr[mid] < val) lo = mid + 1; else hi = mid; }
  return lo;
}

// Per-batch atom segment sums: node_hiddens (B,H), center_pos (B,3)
__global__ void k_atoms(const float* __restrict__ hctx, const float* __restrict__ pos,
                        const int* __restrict__ ab, float* __restrict__ nh,
                        float* __restrict__ center) {
  int b = blockIdx.x, t = threadIdx.x;
  int s = lower_bound_i(ab, NATOMS, b);
  int e = lower_bound_i(ab, NATOMS, b + 1);
  float acc = 0.f;
  for (int a = s; a < e; ++a) acc += hctx[(size_t)a * HD + t];
  nh[(size_t)b * HD + t] = acc;
  if (t < 3) {
    float ps = 0.f;
    for (int a = s; a < e; ++a) ps += pos[a * 3 + t];
    center[b * 3 + t] = ps / fmaxf((float)(e - s), 1.0f);
  }
}

// Per-batch residue masked segment sum: residue_emb (B,H)
__global__ void k_res(const float* __restrict__ hres, const float* __restrict__ rpos,
                      const int* __restrict__ rb, const float* __restrict__ center,
                      float* __restrict__ re) {
  int b = blockIdx.x, t = threadIdx.x;
  int s = lower_bound_i(rb, NRES, b);
  int e = lower_bound_i(rb, NRES, b + 1);
  float c0 = center[b * 3], c1 = center[b * 3 + 1], c2 = center[b * 3 + 2];
  float acc = 0.f;
  for (int r = s; r < e; ++r) {
    float dx = rpos[(size_t)r * 9 + 3] - c0;
    float dy = rpos[(size_t)r * 9 + 4] - c1;
    float dz = rpos[(size_t)r * 9 + 5] - c2;
    if (dx * dx + dy * dy + dz * dz < 36.0f)  // dist < 6
      acc += hres[(size_t)r * HD + t];
  }
  re[(size_t)b * HD + t] = acc;
}

// sum_proto -> inv_sp[p] = 1/(sum+1)
__global__ void k_sumproto(const float* __restrict__ pcnt, float* __restrict__ inv_sp) {
  int p = blockIdx.x, t = threadIdx.x;
  __shared__ float red[256];
  float s = 0.f;
  for (int v = t; v < NV; v += 256) s += pcnt[(size_t)p * NV + v];
  red[t] = s; __syncthreads();
  for (int off = 128; off > 0; off >>= 1) { if (t < off) red[t] += red[t + off]; __syncthreads(); }
  if (t == 0) inv_sp[p] = 1.0f / (red[0] + 1.0f);
}

// wl[v] = log((1+P)/(1+sum_motif[v])) + 1
__global__ void k_wl(const float* __restrict__ pcnt, float* __restrict__ wl) {
  int v = blockIdx.x * blockDim.x + threadIdx.x;
  if (v >= NV) return;
  float sm = 0.f;
  for (int p = 0; p < NP; ++p) sm += (pcnt[(size_t)p * NV + v] > 0.f) ? 1.f : 0.f;
  wl[v] = logf((1.0f + NP) / (1.0f + sm)) + 1.0f;
}

// hin[p] += inv_sp[p] * sum_{v in chunk} pcnt[p,v]*wl[v]*emb[v]   (split-K, atomic)
__global__ void k_bemb2(const float* __restrict__ pcnt, const float* __restrict__ wl,
                        const float* __restrict__ inv_sp, const float* __restrict__ emb,
                        float* __restrict__ hin) {
  int p = blockIdx.x, c = blockIdx.y, t = threadIdx.x;
  __shared__ float cw[VCHUNK];
  int v0 = c * VCHUNK;
  float isp = inv_sp[p];
  for (int v = t; v < VCHUNK; v += 256) cw[v] = pcnt[(size_t)p * NV + v0 + v] * wl[v0 + v] * isp;
  __syncthreads();
  float acc = 0.f;
#pragma unroll 5
  for (int v = 0; v < VCHUNK; ++v) acc += cw[v] * emb[(size_t)(v0 + v) * HD + t];
  atomicAdd(&hin[p * HD + t], acc);
}

// l2-normalized prototypes, stored transposed: pnT[h*P+p]
__global__ void k_proton(const float* __restrict__ proto, float* __restrict__ pnT) {
  int p = blockIdx.x, t = threadIdx.x;
  __shared__ float red[256];
  float x = proto[p * HD + t];
  red[t] = x * x; __syncthreads();
  for (int off = 128; off > 0; off >>= 1) { if (t < off) red[t] += red[t + off]; __syncthreads(); }
  float inv = 1.0f / fmaxf(sqrtf(red[0]), 1e-12f);
  pnT[t * NP + p] = x * inv;
}

// cos = l2norm(re[b]) . pn[p]; top-4 -> knn; then scatter re[b] into hin rows (atomic)
__global__ void k_costopk(const float* __restrict__ re, const float* __restrict__ pnT,
                          int* __restrict__ knn, float* __restrict__ hin) {
  int b = blockIdx.x, t = threadIdx.x;  // 128 threads
  __shared__ float sre[HD];
  __shared__ float red[128];
  __shared__ float c[NP];
  __shared__ float rv[128];
  __shared__ int   ri[128];
  __shared__ int   kk[4];
  float x0 = re[(size_t)b * HD + t], x1 = re[(size_t)b * HD + 128 + t];
  sre[t] = x0; sre[128 + t] = x1;
  red[t] = x0 * x0 + x1 * x1;
  __syncthreads();
  for (int off = 64; off > 0; off >>= 1) { if (t < off) red[t] += red[t + off]; __syncthreads(); }
  float invn = 1.0f / fmaxf(sqrtf(red[0]), 1e-12f);
  float d = 0.f;
  for (int h = 0; h < HD; ++h) d += sre[h] * pnT[h * NP + t];
  c[t] = d * invn;
  __syncthreads();
  for (int k = 0; k < 4; ++k) {
    rv[t] = c[t]; ri[t] = t; __syncthreads();
    for (int off = 64; off > 0; off >>= 1) {
      if (t < off) {
        float ov = rv[t + off]; int oi = ri[t + off];
        if (ov > rv[t] || (ov == rv[t] && oi < ri[t])) { rv[t] = ov; ri[t] = oi; }
      }
      __syncthreads();
    }
    int best = ri[0];
    if (t == 0) { knn[b * 4 + k] = best; kk[k] = best; }
    if (t == best) c[t] = -INFINITY;
    __syncthreads();
  }
  // scatter: hin[p] += re[b] for each of the 4 knn prototypes
#pragma unroll
  for (int k = 0; k < 4; ++k) {
    int p = kk[k];
    atomicAdd(&hin[p * HD + t], sre[t]);
    atomicAdd(&hin[p * HD + 128 + t], sre[128 + t]);
  }
}

// h1p[p] = relu(hin[p] @ gnn_w1)
__global__ void k_h1(const float* __restrict__ hin, const float* __restrict__ w1,
                     float* __restrict__ h1p) {
  int p = blockIdx.x, t = threadIdx.x;
  __shared__ float s[HD];
  s[t] = hin[p * HD + t];
  __syncthreads();
  float acc = 0.f;
  for (int h = 0; h < HD; ++h) acc += s[h] * w1[h * HD + t];
  h1p[p * HD + t] = fmaxf(acc, 0.f);
}

// ro[b] = (sum_{k} h1p[knn[b][k]]) @ gnn_w2   (8 rows per block)
__global__ void k_ro(const int* __restrict__ knn, const float* __restrict__ h1p,
                     const float* __restrict__ w2, float* __restrict__ ro) {
  int b0 = blockIdx.x * 8, t = threadIdx.x;
  __shared__ float s[8][HD];
  for (int i = 0; i < 8; ++i) {
    int4 kn = ((const int4*)knn)[b0 + i];
    s[i][t] = h1p[kn.x * HD + t] + h1p[kn.y * HD + t] + h1p[kn.z * HD + t] + h1p[kn.w * HD + t];
  }
  __syncthreads();
  float acc[8] = {};
  for (int h = 0; h < HD; ++h) {
    float w = w2[h * HD + t];
#pragma unroll
    for (int i = 0; i < 8; ++i) acc[i] += s[i][h] * w;
  }
  for (int i = 0; i < 8; ++i) ro[(size_t)(b0 + i) * HD + t] = acc[i];
}

// U[b] = [0.8*nh[b] | 0.7*emb[wid[b]] | 1.5*ro[b]]
__global__ void k_buildU(const float* __restrict__ nh, const float* __restrict__ emb,
                         const int* __restrict__ wid, const float* __restrict__ ro,
                         float* __restrict__ U) {
  int b = blockIdx.x, t = threadIdx.x;
  U[(size_t)b * 768 + t]       = 0.8f * nh[(size_t)b * HD + t];
  U[(size_t)b * 768 + 256 + t] = 0.7f * emb[(size_t)wid[b] * HD + t];
  U[(size_t)b * 768 + 512 + t] = 1.5f * ro[(size_t)b * HD + t];
}

// Split-bf16 MFMA GEMM: C(MxN) = A(MxK) @ B [+ bias]
// BT=false: B is row-major KxN.  BT=true: B is row-major NxK (i.e. B^T given).
// Each f32 x = hi(bf16) + lo(bf16); product via 3 MFMAs (hh, hl, lh), f32 accum.
// Fragment layout (m89-verified): A row=lane&15, k=(lane>>4)*8+i; B^T staged [n][k] same;
// D: col=lane&15, row=(lane>>4)*4+reg.
template <bool BT>
__global__ __launch_bounds__(256) void k_gemm_mfma(const float* __restrict__ A,
                                                   const float* __restrict__ B,
                                                   const float* __restrict__ bias,
                                                   float* __restrict__ C,
                                                   int M, int N, int K) {
  __shared__ __align__(16) unsigned short Ah[64][40], Al[64][40], Bh[64][40], Bl[64][40];
  int tid = threadIdx.x;
  int lane = tid & 63, w = tid >> 6;
  int wm = (w & 1) * 32, wn = (w >> 1) * 32;
  int bm = blockIdx.x * 64, bn = blockIdx.y * 64;
  f32x4 acc[2][2] = {};

  for (int k0 = 0; k0 < K; k0 += 32) {
    __syncthreads();
    // stage A tile 64x32 (rows bm..bm+63, cols k0..k0+31), split hi/lo
    for (int i = tid; i < 64 * 32; i += 256) {
      int m = i >> 5, k = i & 31;
      float x = A[(size_t)(bm + m) * K + k0 + k];
      unsigned short h = f2bf(x);
      Ah[m][k] = h;
      Al[m][k] = f2bf(x - bf2f(h));
    }
    // stage B as [n][k]
    if (BT) {
      for (int i = tid; i < 64 * 32; i += 256) {
        int n = i >> 5, k = i & 31;
        int col = bn + n;
        float x = (col < N) ? B[(size_t)col * K + k0 + k] : 0.f;
        unsigned short h = f2bf(x);
        Bh[n][k] = h;
        Bl[n][k] = f2bf(x - bf2f(h));
      }
    } else {
      for (int i = tid; i < 32 * 64; i += 256) {
        int k = i >> 6, n = i & 63;
        int col = bn + n;
        float x = (col < N) ? B[(size_t)(k0 + k) * N + col] : 0.f;
        unsigned short h = f2bf(x);
        Bh[n][k] = h;
        Bl[n][k] = f2bf(x - bf2f(h));
      }
    }
    __syncthreads();

    int r = lane & 15, kb = (lane >> 4) * 8;
    bf16x8 ah[2], al[2], bh[2], bl[2];
#pragma unroll
    for (int im = 0; im < 2; ++im) {
      ah[im] = *(const bf16x8*)&Ah[wm + im * 16 + r][kb];
      al[im] = *(const bf16x8*)&Al[wm + im * 16 + r][kb];
    }
#pragma unroll
    for (int in = 0; in < 2; ++in) {
      bh[in] = *(const bf16x8*)&Bh[wn + in * 16 + r][kb];
      bl[in] = *(const bf16x8*)&Bl[wn + in * 16 + r][kb];
    }
#pragma unroll
    for (int im = 0; im < 2; ++im)
#pragma unroll
      for (int in = 0; in < 2; ++in) {
        acc[im][in] = __builtin_amdgcn_mfma_f32_16x16x32_bf16(ah[im], bh[in], acc[im][in], 0, 0, 0);
        acc[im][in] = __builtin_amdgcn_mfma_f32_16x16x32_bf16(ah[im], bl[in], acc[im][in], 0, 0, 0);
        acc[im][in] = __builtin_amdgcn_mfma_f32_16x16x32_bf16(al[im], bh[in], acc[im][in], 0, 0, 0);
      }
  }

  int col0 = lane & 15, row0 = (lane >> 4) * 4;
#pragma unroll
  for (int im = 0; im < 2; ++im)
#pragma unroll
    for (int in = 0; in < 2; ++in) {
      int col = bn + wn + in * 16 + col0;
      if (col < N) {
        float bv = bias ? bias[col] : 0.f;
#pragma unroll
        for (int rr = 0; rr < 4; ++rr) {
          int row = bm + wm + im * 16 + row0 + rr;
          C[(size_t)row * N + col] = acc[im][in][rr] + bv;
        }
      }
    }
}

extern "C" void kernel_launch(void* const* d_in, const int* in_sizes, int n_in,
                              void* d_out, int out_size, void* d_ws, size_t ws_size,
                              hipStream_t stream) {
  const float* hctx  = (const float*)d_in[0];
  const float* pos   = (const float*)d_in[1];
  const float* hres  = (const float*)d_in[2];
  const float* rpos  = (const float*)d_in[3];
  const float* emb   = (const float*)d_in[4];
  const float* proto = (const float*)d_in[5];
  const float* pcnt  = (const float*)d_in[6];
  const float* mw    = (const float*)d_in[7];
  const float* mb    = (const float*)d_in[8];
  const float* w1    = (const float*)d_in[9];
  const float* w2    = (const float*)d_in[10];
  const int* wid     = (const int*)d_in[11];
  const int* ab      = (const int*)d_in[12];
  const int* rb      = (const int*)d_in[13];
  float* out = (float*)d_out;

  // workspace layout (floats), all 16B-aligned
  float* ws     = (float*)d_ws;
  float* nh     = ws;                       // NB*HD
  float* center = nh + (size_t)NB * HD;     // NB*4 (uses 3)
  float* re     = center + (size_t)NB * 4;  // NB*HD
  float* inv_sp = re + (size_t)NB * HD;     // NP
  float* wl     = inv_sp + NP;              // NV
  float* pnT    = wl + NV;                  // HD*NP
  float* hin    = pnT + NP * HD;            // NP*HD  (zeroed; bemb + knn-scatter accumulate)
  float* h1p    = hin + NP * HD;            // NP*HD
  float* ro     = h1p + NP * HD;            // NB*HD
  float* U      = ro + (size_t)NB * HD;     // NB*768
  float* tb     = U + (size_t)NB * 768;     // NB*HD
  int*   knn    = (int*)(tb + (size_t)NB * HD);  // NB*4 ints, 16B aligned

  hipMemsetAsync(hin, 0, (size_t)NP * HD * sizeof(float), stream);
  k_atoms<<<NB, 256, 0, stream>>>(hctx, pos, ab, nh, center);
  k_res<<<NB, 256, 0, stream>>>(hres, rpos, rb, center, re);
  k_sumproto<<<NP, 256, 0, stream>>>(pcnt, inv_sp);
  k_wl<<<(NV + 255) / 256, 256, 0, stream>>>(pcnt, wl);
  k_bemb2<<<dim3(NP, 16), 256, 0, stream>>>(pcnt, wl, inv_sp, emb, hin);
  k_proton<<<NP, 256, 0, stream>>>(proto, pnT);
  k_costopk<<<NB, 128, 0, stream>>>(re, pnT, knn, hin);
  k_h1<<<NP, 256, 0, stream>>>(hin, w1, h1p);
  k_ro<<<NB / 8, 256, 0, stream>>>(knn, h1p, w2, ro);
  k_buildU<<<NB, 256, 0, stream>>>(nh, emb, wid, ro, U);
  // t = U @ motif_w + motif_b   (4096x768 @ 768x256), mw row-major KxN
  k_gemm_mfma<false><<<dim3(NB / 64, 4), 256, 0, stream>>>(U, mw, mb, tb, NB, 256, 768);
  // scores = t @ emb.T          (4096x256 @ 256x2001); emb (2001x256) is B^T row-major
  k_gemm_mfma<true><<<dim3(NB / 64, 32), 256, 0, stream>>>(tb, emb, nullptr, out, NB, 2001, 256);
}

// Round 8
// 646.499 us; speedup vs baseline: 2.1258x; 1.2502x over previous
//
#include <hip/hip_runtime.h>
#include <hip/hip_bf16.h>
#include <math.h>

#define NB 4096
#define HD 256
#define NP 128
#define NV 2000
#define NATOMS 32768
#define NRES 262144
#define VCHUNK 125  // 2000 = 16 * 125

typedef __attribute__((ext_vector_type(8))) short bf16x8;
typedef __attribute__((ext_vector_type(4))) float f32x4;
typedef __attribute__((ext_vector_type(4))) unsigned short u16x4;

__device__ __forceinline__ unsigned short f2bf(float f) {
  unsigned int u = __builtin_bit_cast(unsigned int, f);
  u += 0x7FFFu + ((u >> 16) & 1u);  // RNE
  return (unsigned short)(u >> 16);
}
__device__ __forceinline__ float bf2f(unsigned short h) {
  unsigned int u = ((unsigned int)h) << 16;
  return __builtin_bit_cast(float, u);
}

__device__ __forceinline__ int lower_bound_i(const int* __restrict__ arr, int n, int val) {
  int lo = 0, hi = n;
  while (lo < hi) { int mid = (lo + hi) >> 1; if (arr[mid] < val) lo = mid + 1; else hi = mid; }
  return lo;
}

// k_init block-role boundaries (exclusive ends)
#define E_ATOMS 4096
#define E_SP    (E_ATOMS + 128)   // sum_proto
#define E_WL    (E_SP + 8)        // wl
#define E_PR    (E_WL + 128)      // proton normalize
#define E_HZ    (E_PR + 128)      // hin zero
#define E_ES    (E_HZ + 512)      // emb split (2001*256 elems, x4/thread)
#define E_MS    (E_ES + 192)      // mw^T split (768*256 elems, x4/thread)

// Mega-init: atoms segsum + sumproto + wl + proton + hin=0 + emb/mw bf16-splits
__global__ __launch_bounds__(256) void k_init(
    const float* __restrict__ hctx, const float* __restrict__ pos, const int* __restrict__ ab,
    const float* __restrict__ pcnt, const float* __restrict__ proto,
    const float* __restrict__ emb, const float* __restrict__ mw,
    float* __restrict__ nh, float* __restrict__ center, float* __restrict__ inv_sp,
    float* __restrict__ wl, float* __restrict__ pnT, float* __restrict__ hin,
    unsigned short* __restrict__ embH, unsigned short* __restrict__ embL,
    unsigned short* __restrict__ mwTH, unsigned short* __restrict__ mwTL) {
  int blk = blockIdx.x, t = threadIdx.x;
  __shared__ float red[256];
  if (blk < E_ATOMS) {
    int b = blk;
    int s = lower_bound_i(ab, NATOMS, b);
    int e = lower_bound_i(ab, NATOMS, b + 1);
    float acc = 0.f;
    for (int a = s; a < e; ++a) acc += hctx[(size_t)a * HD + t];
    nh[(size_t)b * HD + t] = acc;
    if (t < 3) {
      float ps = 0.f;
      for (int a = s; a < e; ++a) ps += pos[a * 3 + t];
      center[b * 3 + t] = ps / fmaxf((float)(e - s), 1.0f);
    }
  } else if (blk < E_SP) {
    int p = blk - E_ATOMS;
    float s = 0.f;
    for (int v = t; v < NV; v += 256) s += pcnt[(size_t)p * NV + v];
    red[t] = s; __syncthreads();
    for (int off = 128; off; off >>= 1) { if (t < off) red[t] += red[t + off]; __syncthreads(); }
    if (!t) inv_sp[p] = 1.0f / (red[0] + 1.0f);
  } else if (blk < E_WL) {
    int v = (blk - E_SP) * 256 + t;
    if (v < NV) {
      float sm = 0.f;
      for (int p = 0; p < NP; ++p) sm += (pcnt[(size_t)p * NV + v] > 0.f) ? 1.f : 0.f;
      wl[v] = logf((1.0f + NP) / (1.0f + sm)) + 1.0f;
    }
  } else if (blk < E_PR) {
    int p = blk - E_WL;
    float x = proto[p * HD + t];
    red[t] = x * x; __syncthreads();
    for (int off = 128; off; off >>= 1) { if (t < off) red[t] += red[t + off]; __syncthreads(); }
    float inv = 1.0f / fmaxf(sqrtf(red[0]), 1e-12f);
    pnT[t * NP + p] = x * inv;
  } else if (blk < E_HZ) {
    hin[(blk - E_PR) * 256 + t] = 0.f;
  } else if (blk < E_ES) {
    int e0 = ((blk - E_HZ) * 256 + t) * 4;
#pragma unroll
    for (int j = 0; j < 4; ++j) {
      int e = e0 + j;
      if (e < 2001 * HD) {
        float x = emb[e];
        unsigned short h = f2bf(x);
        embH[e] = h; embL[e] = f2bf(x - bf2f(h));
      }
    }
  } else {
    int e0 = ((blk - E_ES) * 256 + t) * 4;  // e < 196608 exact
#pragma unroll
    for (int j = 0; j < 4; ++j) {
      int e = e0 + j;
      int n = e / 768, k = e - n * 768;     // mwT[n][k] = mw[k][n]
      float x = mw[(size_t)k * HD + n];
      unsigned short h = f2bf(x);
      mwTH[e] = h; mwTL[e] = f2bf(x - bf2f(h));
    }
  }
}

// Fused: residue masked segsum (compaction, latency-fixed) + bemb split-K atomic
__global__ __launch_bounds__(256) void k_res_bemb(
    const float* __restrict__ hres, const float* __restrict__ rpos,
    const int* __restrict__ rb, const float* __restrict__ center,
    const float* __restrict__ pcnt, const float* __restrict__ wl,
    const float* __restrict__ inv_sp, const float* __restrict__ emb,
    float* __restrict__ re, float* __restrict__ hin) {
  int blk = blockIdx.x, t = threadIdx.x;
  __shared__ int lst[256];
  __shared__ int cnt;
  __shared__ float cw[VCHUNK];
  if (blk < NB) {
    int b = blk;
    int s = lower_bound_i(rb, NRES, b);
    int e = lower_bound_i(rb, NRES, b + 1);
    float c0 = center[b * 3], c1 = center[b * 3 + 1], c2 = center[b * 3 + 2];
    float acc = 0.f;
    for (int c = s; c < e; c += 256) {
      if (!t) cnt = 0;
      __syncthreads();
      int r = c + t;
      if (r < e) {
        float dx = rpos[(size_t)r * 9 + 3] - c0;
        float dy = rpos[(size_t)r * 9 + 4] - c1;
        float dz = rpos[(size_t)r * 9 + 5] - c2;
        if (dx * dx + dy * dy + dz * dz < 36.0f) {
          int j = atomicAdd(&cnt, 1);
          lst[j] = r;
        }
      }
      __syncthreads();
      int n = cnt;
      for (int j = 0; j < n; ++j) acc += hres[(size_t)lst[j] * HD + t];  // unconditional, pipelined
      __syncthreads();
    }
    re[(size_t)b * HD + t] = acc;
  } else {
    int pc = blk - NB;
    int p = pc >> 4, c = pc & 15;
    int v0 = c * VCHUNK;
    float isp = inv_sp[p];
    for (int v = t; v < VCHUNK; v += 256) cw[v] = pcnt[(size_t)p * NV + v0 + v] * wl[v0 + v] * isp;
    __syncthreads();
    float acc = 0.f;
#pragma unroll 5
    for (int v = 0; v < VCHUNK; ++v) acc += cw[v] * emb[(size_t)(v0 + v) * HD + t];
    atomicAdd(&hin[p * HD + t], acc);
  }
}

// cos + top-4 + scatter re into hin (256 threads; split dot over 2 halves)
__global__ __launch_bounds__(256) void k_costopk(const float* __restrict__ re,
                                                 const float* __restrict__ pnT,
                                                 int* __restrict__ knn, float* __restrict__ hin) {
  int b = blockIdx.x, t = threadIdx.x;
  __shared__ float sre[HD];
  __shared__ float part[256];
  __shared__ float c[NP];
  __shared__ float rv[256];
  __shared__ int ri[256];
  __shared__ int kk[4];
  float x = re[(size_t)b * HD + t];
  sre[t] = x;
  part[t] = x * x;
  __syncthreads();
  for (int off = 128; off; off >>= 1) { if (t < off) part[t] += part[t + off]; __syncthreads(); }
  float invn = 1.0f / fmaxf(sqrtf(part[0]), 1e-12f);
  __syncthreads();
  int p = t & 127, half = t >> 7;
  float d = 0.f;
  int h0 = half * 128;
  for (int h = h0; h < h0 + 128; ++h) d += sre[h] * pnT[h * NP + p];
  part[t] = d;
  __syncthreads();
  if (t < NP) c[t] = (part[t] + part[t + 128]) * invn;
  __syncthreads();
  for (int k = 0; k < 4; ++k) {
    rv[t] = (t < NP) ? c[t] : -INFINITY;
    ri[t] = t;
    __syncthreads();
    for (int off = 128; off; off >>= 1) {
      if (t < off) {
        float ov = rv[t + off]; int oi = ri[t + off];
        if (ov > rv[t] || (ov == rv[t] && oi < ri[t])) { rv[t] = ov; ri[t] = oi; }
      }
      __syncthreads();
    }
    if (!t) { knn[b * 4 + k] = ri[0]; kk[k] = ri[0]; }
    if (t == ri[0]) c[t] = -INFINITY;
    __syncthreads();
  }
#pragma unroll
  for (int k = 0; k < 4; ++k) atomicAdd(&hin[kk[k] * HD + t], sre[t]);
}

// hw[p] = (relu(hin[p] @ w1)) @ w2   (128 blocks)
__global__ __launch_bounds__(256) void k_h1hw(const float* __restrict__ hin,
                                              const float* __restrict__ w1,
                                              const float* __restrict__ w2,
                                              float* __restrict__ hw) {
  int p = blockIdx.x, t = threadIdx.x;
  __shared__ float s[HD], s2[HD];
  s[t] = hin[p * HD + t];
  __syncthreads();
  float a = 0.f;
  for (int h = 0; h < HD; ++h) a += s[h] * w1[h * HD + t];
  s2[t] = fmaxf(a, 0.f);
  __syncthreads();
  float o = 0.f;
  for (int h = 0; h < HD; ++h) o += s2[h] * w2[h * HD + t];
  hw[p * HD + t] = o;
}

// GEMM1: tb = U @ mw + mb, with U generated on the fly:
// U[:,0:256)=0.8*nh, [256:512)=0.7*emb[wid], [512:768)=1.5*(hw[knn].sum)
// B pre-split transposed (mwT [n][k]). Output written as split bf16 (tbH/tbL).
__global__ __launch_bounds__(256) void k_gemm1(
    const float* __restrict__ nh, const float* __restrict__ emb,
    const int* __restrict__ wid, const int* __restrict__ knn, const float* __restrict__ hw,
    const unsigned short* __restrict__ mwTH, const unsigned short* __restrict__ mwTL,
    const float* __restrict__ mb,
    unsigned short* __restrict__ tbH, unsigned short* __restrict__ tbL) {
  __shared__ __align__(16) unsigned short Ah[64][40], Al[64][40], Bh[64][40], Bl[64][40];
  __shared__ int swid[64];
  __shared__ int4 sknn[64];
  int tid = threadIdx.x, lane = tid & 63, w = tid >> 6;
  int wm = (w & 1) * 32, wn = (w >> 1) * 32;
  int bm = blockIdx.x * 64, bn = blockIdx.y * 64;
  if (tid < 64) { swid[tid] = wid[bm + tid]; sknn[tid] = ((const int4*)knn)[bm + tid]; }
  f32x4 acc[2][2] = {};
  for (int k0 = 0; k0 < 768; k0 += 32) {
    __syncthreads();
    if (k0 < 256) {
      for (int i = tid; i < 2048; i += 256) {
        int m = i >> 5, k = i & 31;
        float x = 0.8f * nh[(size_t)(bm + m) * HD + k0 + k];
        unsigned short h = f2bf(x);
        Ah[m][k] = h; Al[m][k] = f2bf(x - bf2f(h));
      }
    } else if (k0 < 512) {
      for (int i = tid; i < 2048; i += 256) {
        int m = i >> 5, k = i & 31;
        float x = 0.7f * emb[(size_t)swid[m] * HD + (k0 - 256) + k];
        unsigned short h = f2bf(x);
        Ah[m][k] = h; Al[m][k] = f2bf(x - bf2f(h));
      }
    } else {
      for (int i = tid; i < 2048; i += 256) {
        int m = i >> 5, k = i & 31;
        int4 kn = sknn[m];
        int kk = (k0 - 512) + k;
        float x = 1.5f * (hw[kn.x * HD + kk] + hw[kn.y * HD + kk] +
                          hw[kn.z * HD + kk] + hw[kn.w * HD + kk]);
        unsigned short h = f2bf(x);
        Ah[m][k] = h; Al[m][k] = f2bf(x - bf2f(h));
      }
    }
    for (int i = tid; i < 2048; i += 256) {
      int n = i >> 5, k = i & 31;
      size_t idx = (size_t)(bn + n) * 768 + k0 + k;
      Bh[n][k] = mwTH[idx];
      Bl[n][k] = mwTL[idx];
    }
    __syncthreads();
    int r = lane & 15, kb = (lane >> 4) * 8;
    bf16x8 ah[2], al[2], bh[2], bl[2];
#pragma unroll
    for (int im = 0; im < 2; ++im) {
      ah[im] = *(const bf16x8*)&Ah[wm + im * 16 + r][kb];
      al[im] = *(const bf16x8*)&Al[wm + im * 16 + r][kb];
    }
#pragma unroll
    for (int in = 0; in < 2; ++in) {
      bh[in] = *(const bf16x8*)&Bh[wn + in * 16 + r][kb];
      bl[in] = *(const bf16x8*)&Bl[wn + in * 16 + r][kb];
    }
#pragma unroll
    for (int im = 0; im < 2; ++im)
#pragma unroll
      for (int in = 0; in < 2; ++in) {
        acc[im][in] = __builtin_amdgcn_mfma_f32_16x16x32_bf16(ah[im], bh[in], acc[im][in], 0, 0, 0);
        acc[im][in] = __builtin_amdgcn_mfma_f32_16x16x32_bf16(ah[im], bl[in], acc[im][in], 0, 0, 0);
        acc[im][in] = __builtin_amdgcn_mfma_f32_16x16x32_bf16(al[im], bh[in], acc[im][in], 0, 0, 0);
      }
  }
  int col0 = lane & 15, row0 = (lane >> 4) * 4;
#pragma unroll
  for (int im = 0; im < 2; ++im)
#pragma unroll
    for (int in = 0; in < 2; ++in) {
      int col = bn + wn + in * 16 + col0;
      float bv = mb[col];
#pragma unroll
      for (int rr = 0; rr < 4; ++rr) {
        int row = bm + wm + im * 16 + row0 + rr;
        float x = acc[im][in][rr] + bv;
        unsigned short h = f2bf(x);
        tbH[(size_t)row * HD + col] = h;
        tbL[(size_t)row * HD + col] = f2bf(x - bf2f(h));
      }
    }
}

// GEMM2: out = tb @ emb^T  (A/B both pre-split bf16; staging = pure ushort4 copies)
__global__ __launch_bounds__(256) void k_gemm2(
    const unsigned short* __restrict__ tbH, const unsigned short* __restrict__ tbL,
    const unsigned short* __restrict__ embH, const unsigned short* __restrict__ embL,
    float* __restrict__ out) {
  __shared__ __align__(16) unsigned short Ah[64][40], Al[64][40], Bh[64][40], Bl[64][40];
  int tid = threadIdx.x, lane = tid & 63, w = tid >> 6;
  int wm = (w & 1) * 32, wn = (w >> 1) * 32;
  int bm = blockIdx.x * 64, bn = blockIdx.y * 64;
  f32x4 acc[2][2] = {};
  for (int k0 = 0; k0 < HD; k0 += 32) {
    __syncthreads();
    for (int i4 = tid; i4 < 512; i4 += 256) {
      int e = i4 * 4, m = e >> 5, k = e & 31;
      *(u16x4*)&Ah[m][k] = *(const u16x4*)&tbH[(size_t)(bm + m) * HD + k0 + k];
      *(u16x4*)&Al[m][k] = *(const u16x4*)&tbL[(size_t)(bm + m) * HD + k0 + k];
    }
    for (int i4 = tid; i4 < 512; i4 += 256) {
      int e = i4 * 4, n = e >> 5, k = e & 31;
      int col = bn + n;
      if (col <= 2000) {
        *(u16x4*)&Bh[n][k] = *(const u16x4*)&embH[(size_t)col * HD + k0 + k];
        *(u16x4*)&Bl[n][k] = *(const u16x4*)&embL[(size_t)col * HD + k0 + k];
      } else {
        u16x4 z = (u16x4)0;
        *(u16x4*)&Bh[n][k] = z;
        *(u16x4*)&Bl[n][k] = z;
      }
    }
    __syncthreads();
    int r = lane & 15, kb = (lane >> 4) * 8;
    bf16x8 ah[2], al[2], bh[2], bl[2];
#pragma unroll
    for (int im = 0; im < 2; ++im) {
      ah[im] = *(const bf16x8*)&Ah[wm + im * 16 + r][kb];
      al[im] = *(const bf16x8*)&Al[wm + im * 16 + r][kb];
    }
#pragma unroll
    for (int in = 0; in < 2; ++in) {
      bh[in] = *(const bf16x8*)&Bh[wn + in * 16 + r][kb];
      bl[in] = *(const bf16x8*)&Bl[wn + in * 16 + r][kb];
    }
#pragma unroll
    for (int im = 0; im < 2; ++im)
#pragma unroll
      for (int in = 0; in < 2; ++in) {
        acc[im][in] = __builtin_amdgcn_mfma_f32_16x16x32_bf16(ah[im], bh[in], acc[im][in], 0, 0, 0);
        acc[im][in] = __builtin_amdgcn_mfma_f32_16x16x32_bf16(ah[im], bl[in], acc[im][in], 0, 0, 0);
        acc[im][in] = __builtin_amdgcn_mfma_f32_16x16x32_bf16(al[im], bh[in], acc[im][in], 0, 0, 0);
      }
  }
  int col0 = lane & 15, row0 = (lane >> 4) * 4;
#pragma unroll
  for (int im = 0; im < 2; ++im)
#pragma unroll
    for (int in = 0; in < 2; ++in) {
      int col = bn + wn + in * 16 + col0;
      if (col <= 2000) {
#pragma unroll
        for (int rr = 0; rr < 4; ++rr) {
          int row = bm + wm + im * 16 + row0 + rr;
          out[(size_t)row * 2001 + col] = acc[im][in][rr];
        }
      }
    }
}

extern "C" void kernel_launch(void* const* d_in, const int* in_sizes, int n_in,
                              void* d_out, int out_size, void* d_ws, size_t ws_size,
                              hipStream_t stream) {
  const float* hctx  = (const float*)d_in[0];
  const float* pos   = (const float*)d_in[1];
  const float* hres  = (const float*)d_in[2];
  const float* rpos  = (const float*)d_in[3];
  const float* emb   = (const float*)d_in[4];
  const float* proto = (const float*)d_in[5];
  const float* pcnt  = (const float*)d_in[6];
  const float* mw    = (const float*)d_in[7];
  const float* mb    = (const float*)d_in[8];
  const float* w1    = (const float*)d_in[9];
  const float* w2    = (const float*)d_in[10];
  const int* wid     = (const int*)d_in[11];
  const int* ab      = (const int*)d_in[12];
  const int* rb      = (const int*)d_in[13];
  float* out = (float*)d_out;

  // workspace layout (float units; every size a multiple of 4 -> 16B alignment)
  float* ws     = (float*)d_ws;
  float* nh     = ws;                            // 1048576
  float* center = nh + (size_t)NB * HD;          // 16384
  float* re     = center + (size_t)NB * 4;       // 1048576
  float* inv_sp = re + (size_t)NB * HD;          // 128
  float* wl     = inv_sp + 128;                  // 2048 (2000 used)
  float* pnT    = wl + 2048;                     // 32768
  float* hin    = pnT + NP * HD;                 // 32768
  float* hw     = hin + NP * HD;                 // 32768
  int*   knn    = (int*)(hw + NP * HD);          // 16384 ints
  unsigned short* tbH  = (unsigned short*)(knn + NB * 4);   // NB*HD ushorts
  unsigned short* tbL  = tbH + (size_t)NB * HD;
  unsigned short* embH = tbL + (size_t)NB * HD;             // 2048*HD ushorts (2001 used)
  unsigned short* embL = embH + (size_t)2048 * HD;
  unsigned short* mwTH = embL + (size_t)2048 * HD;          // 768*HD ushorts (transposed)
  unsigned short* mwTL = mwTH + (size_t)768 * HD;

  k_init<<<E_MS, 256, 0, stream>>>(hctx, pos, ab, pcnt, proto, emb, mw,
                                   nh, center, inv_sp, wl, pnT, hin,
                                   embH, embL, mwTH, mwTL);
  k_res_bemb<<<NB + NP * 16, 256, 0, stream>>>(hres, rpos, rb, center,
                                               pcnt, wl, inv_sp, emb, re, hin);
  k_costopk<<<NB, 256, 0, stream>>>(re, pnT, knn, hin);
  k_h1hw<<<NP, 256, 0, stream>>>(hin, w1, w2, hw);
  k_gemm1<<<dim3(NB / 64, 4), 256, 0, stream>>>(nh, emb, wid, knn, hw,
                                                mwTH, mwTL, mb, tbH, tbL);
  k_gemm2<<<dim3(NB / 64, 32), 256, 0, stream>>>(tbH, tbL, embH, embL, out);
}

// Round 9
// 585.727 us; speedup vs baseline: 2.3464x; 1.1038x over previous
//
#include <hip/hip_runtime.h>
#include <hip/hip_bf16.h>
#include <math.h>

#define NB 4096
#define HD 256
#define NP 128
#define NV 2000
#define NATOMS 32768
#define NRES 262144
#define VCHUNK 125  // 2000 = 16 * 125

typedef __attribute__((ext_vector_type(8))) short bf16x8;
typedef __attribute__((ext_vector_type(4))) float f32x4;
typedef __attribute__((ext_vector_type(8))) unsigned short u16x8;

__device__ __forceinline__ unsigned short f2bf(float f) {
  unsigned int u = __builtin_bit_cast(unsigned int, f);
  u += 0x7FFFu + ((u >> 16) & 1u);  // RNE
  return (unsigned short)(u >> 16);
}
__device__ __forceinline__ float bf2f(unsigned short h) {
  unsigned int u = ((unsigned int)h) << 16;
  return __builtin_bit_cast(float, u);
}

__device__ __forceinline__ int lower_bound_i(const int* __restrict__ arr, int n, int val) {
  int lo = 0, hi = n;
  while (lo < hi) { int mid = (lo + hi) >> 1; if (arr[mid] < val) lo = mid + 1; else hi = mid; }
  return lo;
}

// k_init block-role boundaries (exclusive ends)
#define E_ATOMS 4096
#define E_SP    (E_ATOMS + 128)   // sum_proto
#define E_WL    (E_SP + 8)        // wl
#define E_PR    (E_WL + 128)      // proton normalize
#define E_HZ    (E_PR + 128)      // hin zero
#define E_ES    (E_HZ + 512)      // emb split: 2048*256 elems (zeros past 2001 rows)
#define E_MS    (E_ES + 192)      // mw^T split (768*256)

__global__ __launch_bounds__(256) void k_init(
    const float* __restrict__ hctx, const float* __restrict__ pos, const int* __restrict__ ab,
    const float* __restrict__ pcnt, const float* __restrict__ proto,
    const float* __restrict__ emb, const float* __restrict__ mw,
    float* __restrict__ nh, float* __restrict__ center, float* __restrict__ inv_sp,
    float* __restrict__ wl, float* __restrict__ pnT, float* __restrict__ hin,
    unsigned short* __restrict__ embH, unsigned short* __restrict__ embL,
    unsigned short* __restrict__ mwTH, unsigned short* __restrict__ mwTL) {
  int blk = blockIdx.x, t = threadIdx.x;
  __shared__ float red[256];
  if (blk < E_ATOMS) {
    int b = blk;
    int s = lower_bound_i(ab, NATOMS, b);
    int e = lower_bound_i(ab, NATOMS, b + 1);
    float acc = 0.f;
    for (int a = s; a < e; ++a) acc += hctx[(size_t)a * HD + t];
    nh[(size_t)b * HD + t] = acc;
    if (t < 3) {
      float ps = 0.f;
      for (int a = s; a < e; ++a) ps += pos[a * 3 + t];
      center[b * 3 + t] = ps / fmaxf((float)(e - s), 1.0f);
    }
  } else if (blk < E_SP) {
    int p = blk - E_ATOMS;
    float s = 0.f;
    for (int v = t; v < NV; v += 256) s += pcnt[(size_t)p * NV + v];
    red[t] = s; __syncthreads();
    for (int off = 128; off; off >>= 1) { if (t < off) red[t] += red[t + off]; __syncthreads(); }
    if (!t) inv_sp[p] = 1.0f / (red[0] + 1.0f);
  } else if (blk < E_WL) {
    int v = (blk - E_SP) * 256 + t;
    if (v < NV) {
      float sm = 0.f;
      for (int p = 0; p < NP; ++p) sm += (pcnt[(size_t)p * NV + v] > 0.f) ? 1.f : 0.f;
      wl[v] = logf((1.0f + NP) / (1.0f + sm)) + 1.0f;
    }
  } else if (blk < E_PR) {
    int p = blk - E_WL;
    float x = proto[p * HD + t];
    red[t] = x * x; __syncthreads();
    for (int off = 128; off; off >>= 1) { if (t < off) red[t] += red[t + off]; __syncthreads(); }
    float inv = 1.0f / fmaxf(sqrtf(red[0]), 1e-12f);
    pnT[t * NP + p] = x * inv;
  } else if (blk < E_HZ) {
    hin[(blk - E_PR) * 256 + t] = 0.f;
  } else if (blk < E_ES) {
    int e0 = ((blk - E_HZ) * 256 + t) * 4;  // covers 2048*256 exactly
#pragma unroll
    for (int j = 0; j < 4; ++j) {
      int e = e0 + j;
      if (e < 2001 * HD) {
        float x = emb[e];
        unsigned short h = f2bf(x);
        embH[e] = h; embL[e] = f2bf(x - bf2f(h));
      } else {
        embH[e] = 0; embL[e] = 0;  // pad rows 2001..2047 -> zeros
      }
    }
  } else {
    int e0 = ((blk - E_ES) * 256 + t) * 4;  // 768*256 exact
#pragma unroll
    for (int j = 0; j < 4; ++j) {
      int e = e0 + j;
      int n = e / 768, k = e - n * 768;     // mwT[n][k] = mw[k][n]
      float x = mw[(size_t)k * HD + n];
      unsigned short h = f2bf(x);
      mwTH[e] = h; mwTL[e] = f2bf(x - bf2f(h));
    }
  }
}

// Fused: residue masked segsum (LDS compaction) -> l2norm -> cos -> top4 -> hin scatter.
// Blocks [NB, NB+2048): bemb split-K atomic into hin.
__global__ __launch_bounds__(256) void k_res_topk_bemb(
    const float* __restrict__ hres, const float* __restrict__ rpos,
    const int* __restrict__ rb, const float* __restrict__ center,
    const float* __restrict__ pcnt, const float* __restrict__ wl,
    const float* __restrict__ inv_sp, const float* __restrict__ emb,
    const float* __restrict__ pnT, int* __restrict__ knn, float* __restrict__ hin) {
  int blk = blockIdx.x, t = threadIdx.x;
  __shared__ int lst[256];
  __shared__ int cnt;
  __shared__ float cw[VCHUNK];
  __shared__ float sre[HD];
  __shared__ float part[256];
  __shared__ float c[NP];
  __shared__ float rv[256];
  __shared__ int ri[256];
  __shared__ int kk[4];
  if (blk < NB) {
    int b = blk;
    int s = lower_bound_i(rb, NRES, b);
    int e = lower_bound_i(rb, NRES, b + 1);
    float c0 = center[b * 3], c1 = center[b * 3 + 1], c2 = center[b * 3 + 2];
    float acc = 0.f;
    for (int cc = s; cc < e; cc += 256) {
      if (!t) cnt = 0;
      __syncthreads();
      int r = cc + t;
      if (r < e) {
        float dx = rpos[(size_t)r * 9 + 3] - c0;
        float dy = rpos[(size_t)r * 9 + 4] - c1;
        float dz = rpos[(size_t)r * 9 + 5] - c2;
        if (dx * dx + dy * dy + dz * dz < 36.0f) {
          int j = atomicAdd(&cnt, 1);
          lst[j] = r;
        }
      }
      __syncthreads();
      int n = cnt;
      for (int j = 0; j < n; ++j) acc += hres[(size_t)lst[j] * HD + t];
      __syncthreads();
    }
    // ---- fused costopk (re row lives in registers/LDS only) ----
    sre[t] = acc;
    part[t] = acc * acc;
    __syncthreads();
    for (int off = 128; off; off >>= 1) { if (t < off) part[t] += part[t + off]; __syncthreads(); }
    float invn = 1.0f / fmaxf(sqrtf(part[0]), 1e-12f);
    __syncthreads();
    int p = t & 127, half = t >> 7;
    float d = 0.f;
    int h0 = half * 128;
    for (int h = h0; h < h0 + 128; ++h) d += sre[h] * pnT[h * NP + p];
    part[t] = d;
    __syncthreads();
    if (t < NP) c[t] = (part[t] + part[t + 128]) * invn;
    __syncthreads();
    for (int k = 0; k < 4; ++k) {
      rv[t] = (t < NP) ? c[t] : -INFINITY;
      ri[t] = t;
      __syncthreads();
      for (int off = 128; off; off >>= 1) {
        if (t < off) {
          float ov = rv[t + off]; int oi = ri[t + off];
          if (ov > rv[t] || (ov == rv[t] && oi < ri[t])) { rv[t] = ov; ri[t] = oi; }
        }
        __syncthreads();
      }
      if (!t) { knn[b * 4 + k] = ri[0]; kk[k] = ri[0]; }
      if (t == ri[0]) c[t] = -INFINITY;
      __syncthreads();
    }
#pragma unroll
    for (int k = 0; k < 4; ++k) atomicAdd(&hin[kk[k] * HD + t], sre[t]);
  } else {
    int pc = blk - NB;
    int p = pc >> 4, ch = pc & 15;
    int v0 = ch * VCHUNK;
    float isp = inv_sp[p];
    for (int v = t; v < VCHUNK; v += 256) cw[v] = pcnt[(size_t)p * NV + v0 + v] * wl[v0 + v] * isp;
    __syncthreads();
    float acc = 0.f;
#pragma unroll 5
    for (int v = 0; v < VCHUNK; ++v) acc += cw[v] * emb[(size_t)(v0 + v) * HD + t];
    atomicAdd(&hin[p * HD + t], acc);
  }
}

// hw[p] = (relu(hin[p] @ w1)) @ w2
__global__ __launch_bounds__(256) void k_h1hw(const float* __restrict__ hin,
                                              const float* __restrict__ w1,
                                              const float* __restrict__ w2,
                                              float* __restrict__ hw) {
  int p = blockIdx.x, t = threadIdx.x;
  __shared__ float s[HD], s2[HD];
  s[t] = hin[p * HD + t];
  __syncthreads();
  float a = 0.f;
  for (int h = 0; h < HD; ++h) a += s[h] * w1[h * HD + t];
  s2[t] = fmaxf(a, 0.f);
  __syncthreads();
  float o = 0.f;
  for (int h = 0; h < HD; ++h) o += s2[h] * w2[h * HD + t];
  hw[p * HD + t] = o;
}

// GEMM1: tb = U @ mw + mb; U built on the fly. 64x64 tile, 512 threads (8 waves, 2Mx4N).
__global__ __launch_bounds__(512) void k_gemm1(
    const float* __restrict__ nh, const float* __restrict__ emb,
    const int* __restrict__ wid, const int* __restrict__ knn, const float* __restrict__ hw,
    const unsigned short* __restrict__ mwTH, const unsigned short* __restrict__ mwTL,
    const float* __restrict__ mb,
    unsigned short* __restrict__ tbH, unsigned short* __restrict__ tbL) {
  __shared__ __align__(16) unsigned short Ah[64][40], Al[64][40], Bh[64][40], Bl[64][40];
  __shared__ int swid[64];
  __shared__ int4 sknn[64];
  int tid = threadIdx.x, lane = tid & 63, w = tid >> 6;  // w in 0..7
  int wm = (w & 1) * 32, wn = (w >> 1) * 16;
  int bm = blockIdx.x * 64, bn = blockIdx.y * 64;
  if (tid < 64) { swid[tid] = wid[bm + tid]; sknn[tid] = ((const int4*)knn)[bm + tid]; }
  f32x4 acc[2] = {};
  for (int k0 = 0; k0 < 768; k0 += 32) {
    __syncthreads();
    for (int i = tid; i < 2048; i += 512) {
      int m = i >> 5, k = i & 31;
      float x;
      if (k0 < 256) {
        x = 0.8f * nh[(size_t)(bm + m) * HD + k0 + k];
      } else if (k0 < 512) {
        x = 0.7f * emb[(size_t)swid[m] * HD + (k0 - 256) + k];
      } else {
        int4 kn = sknn[m];
        int kk2 = (k0 - 512) + k;
        x = 1.5f * (hw[kn.x * HD + kk2] + hw[kn.y * HD + kk2] +
                    hw[kn.z * HD + kk2] + hw[kn.w * HD + kk2]);
      }
      unsigned short h = f2bf(x);
      Ah[m][k] = h; Al[m][k] = f2bf(x - bf2f(h));
    }
    if (tid < 256) {  // B: 2048 elems as 256 u16x8
      int e = tid * 8, n = e >> 5, k = e & 31;
      size_t idx = (size_t)(bn + n) * 768 + k0 + k;
      *(u16x8*)&Bh[n][k] = *(const u16x8*)&mwTH[idx];
      *(u16x8*)&Bl[n][k] = *(const u16x8*)&mwTL[idx];
    }
    __syncthreads();
    int r = lane & 15, kb = (lane >> 4) * 8;
    bf16x8 bh = *(const bf16x8*)&Bh[wn + r][kb];
    bf16x8 bl = *(const bf16x8*)&Bl[wn + r][kb];
#pragma unroll
    for (int i = 0; i < 2; ++i) {
      bf16x8 ah = *(const bf16x8*)&Ah[wm + i * 16 + r][kb];
      bf16x8 al = *(const bf16x8*)&Al[wm + i * 16 + r][kb];
      acc[i] = __builtin_amdgcn_mfma_f32_16x16x32_bf16(ah, bh, acc[i], 0, 0, 0);
      acc[i] = __builtin_amdgcn_mfma_f32_16x16x32_bf16(ah, bl, acc[i], 0, 0, 0);
      acc[i] = __builtin_amdgcn_mfma_f32_16x16x32_bf16(al, bh, acc[i], 0, 0, 0);
    }
  }
  int col0 = lane & 15, row0 = (lane >> 4) * 4;
  int col = bn + wn + col0;
  float bv = mb[col];
#pragma unroll
  for (int i = 0; i < 2; ++i)
#pragma unroll
    for (int rr = 0; rr < 4; ++rr) {
      int row = bm + wm + i * 16 + row0 + rr;
      float x = acc[i][rr] + bv;
      unsigned short h = f2bf(x);
      tbH[(size_t)row * HD + col] = h;
      tbL[(size_t)row * HD + col] = f2bf(x - bf2f(h));
    }
}

// GEMM2: out = tb @ emb^T. 128x128 tile, 4 waves (2x2 of 64x64), padded LDS, ushort8 staging.
__global__ __launch_bounds__(256) void k_gemm2(
    const unsigned short* __restrict__ tbH, const unsigned short* __restrict__ tbL,
    const unsigned short* __restrict__ embH, const unsigned short* __restrict__ embL,
    float* __restrict__ out) {
  __shared__ __align__(16) unsigned short AH[128][40], AL[128][40], BH[128][40], BL[128][40];
  int tid = threadIdx.x, lane = tid & 63, w = tid >> 6;
  int wm = (w & 1) * 64, wn = (w >> 1) * 64;
  int bm = blockIdx.x * 128, bn = blockIdx.y * 128;
  f32x4 acc[4][4] = {};
  for (int k0 = 0; k0 < HD; k0 += 32) {
    __syncthreads();
#pragma unroll
    for (int cch = 0; cch < 2; ++cch) {
      int e = (tid + cch * 256) * 8;  // 0..4088
      int m = e >> 5, k = e & 31;
      *(u16x8*)&AH[m][k] = *(const u16x8*)&tbH[(size_t)(bm + m) * HD + k0 + k];
      *(u16x8*)&AL[m][k] = *(const u16x8*)&tbL[(size_t)(bm + m) * HD + k0 + k];
      *(u16x8*)&BH[m][k] = *(const u16x8*)&embH[(size_t)(bn + m) * HD + k0 + k];
      *(u16x8*)&BL[m][k] = *(const u16x8*)&embL[(size_t)(bn + m) * HD + k0 + k];
    }
    __syncthreads();
    int r = lane & 15, kb = (lane >> 4) * 8;
    bf16x8 ah[4], al[4], bh[4], bl[4];
#pragma unroll
    for (int i = 0; i < 4; ++i) {
      ah[i] = *(const bf16x8*)&AH[wm + i * 16 + r][kb];
      al[i] = *(const bf16x8*)&AL[wm + i * 16 + r][kb];
      bh[i] = *(const bf16x8*)&BH[wn + i * 16 + r][kb];
      bl[i] = *(const bf16x8*)&BL[wn + i * 16 + r][kb];
    }
#pragma unroll
    for (int i = 0; i < 4; ++i)
#pragma unroll
      for (int j = 0; j < 4; ++j) {
        acc[i][j] = __builtin_amdgcn_mfma_f32_16x16x32_bf16(ah[i], bh[j], acc[i][j], 0, 0, 0);
        acc[i][j] = __builtin_amdgcn_mfma_f32_16x16x32_bf16(ah[i], bl[j], acc[i][j], 0, 0, 0);
        acc[i][j] = __builtin_amdgcn_mfma_f32_16x16x32_bf16(al[i], bh[j], acc[i][j], 0, 0, 0);
      }
  }
  int col0 = lane & 15, row0 = (lane >> 4) * 4;
#pragma unroll
  for (int i = 0; i < 4; ++i)
#pragma unroll
    for (int j = 0; j < 4; ++j) {
      int col = bn + wn + j * 16 + col0;
      if (col <= 2000) {
#pragma unroll
        for (int rr = 0; rr < 4; ++rr) {
          int row = bm + wm + i * 16 + row0 + rr;
          out[(size_t)row * 2001 + col] = acc[i][j][rr];
        }
      }
    }
}

extern "C" void kernel_launch(void* const* d_in, const int* in_sizes, int n_in,
                              void* d_out, int out_size, void* d_ws, size_t ws_size,
                              hipStream_t stream) {
  const float* hctx  = (const float*)d_in[0];
  const float* pos   = (const float*)d_in[1];
  const float* hres  = (const float*)d_in[2];
  const float* rpos  = (const float*)d_in[3];
  const float* emb   = (const float*)d_in[4];
  const float* proto = (const float*)d_in[5];
  const float* pcnt  = (const float*)d_in[6];
  const float* mw    = (const float*)d_in[7];
  const float* mb    = (const float*)d_in[8];
  const float* w1    = (const float*)d_in[9];
  const float* w2    = (const float*)d_in[10];
  const int* wid     = (const int*)d_in[11];
  const int* ab      = (const int*)d_in[12];
  const int* rb      = (const int*)d_in[13];
  float* out = (float*)d_out;

  float* ws     = (float*)d_ws;
  float* nh     = ws;                            // NB*HD
  float* center = nh + (size_t)NB * HD;          // NB*4
  float* inv_sp = center + (size_t)NB * 4;       // 128
  float* wl     = inv_sp + 128;                  // 2048 (2000 used)
  float* pnT    = wl + 2048;                     // HD*NP
  float* hin    = pnT + NP * HD;                 // NP*HD
  float* hw     = hin + NP * HD;                 // NP*HD
  int*   knn    = (int*)(hw + NP * HD);          // NB*4 ints
  unsigned short* tbH  = (unsigned short*)(knn + NB * 4);   // NB*HD
  unsigned short* tbL  = tbH + (size_t)NB * HD;
  unsigned short* embH = tbL + (size_t)NB * HD;             // 2048*HD (rows >=2001 zeroed)
  unsigned short* embL = embH + (size_t)2048 * HD;
  unsigned short* mwTH = embL + (size_t)2048 * HD;          // 768*HD (transposed)
  unsigned short* mwTL = mwTH + (size_t)768 * HD;

  k_init<<<E_MS, 256, 0, stream>>>(hctx, pos, ab, pcnt, proto, emb, mw,
                                   nh, center, inv_sp, wl, pnT, hin,
                                   embH, embL, mwTH, mwTL);
  k_res_topk_bemb<<<NB + NP * 16, 256, 0, stream>>>(hres, rpos, rb, center,
                                                    pcnt, wl, inv_sp, emb, pnT, knn, hin);
  k_h1hw<<<NP, 256, 0, stream>>>(hin, w1, w2, hw);
  k_gemm1<<<dim3(NB / 64, 4), 512, 0, stream>>>(nh, emb, wid, knn, hw,
                                                mwTH, mwTL, mb, tbH, tbL);
  k_gemm2<<<dim3(NB / 128, 16), 256, 0, stream>>>(tbH, tbL, embH, embL, out);
}

// Round 10
// 548.481 us; speedup vs baseline: 2.5057x; 1.0679x over previous
//
#include <hip/hip_runtime.h>
#include <hip/hip_bf16.h>
#include <math.h>

#define NB 4096
#define HD 256
#define NP 128
#define NV 2000
#define NATOMS 32768
#define NRES 262144
#define VCHUNK 125  // 2000 = 16 * 125

typedef __attribute__((ext_vector_type(8))) short bf16x8;
typedef __attribute__((ext_vector_type(4))) float f32x4;
typedef __attribute__((ext_vector_type(8))) unsigned short u16x8;

__device__ __forceinline__ unsigned short f2bf(float f) {
  unsigned int u = __builtin_bit_cast(unsigned int, f);
  u += 0x7FFFu + ((u >> 16) & 1u);  // RNE
  return (unsigned short)(u >> 16);
}
__device__ __forceinline__ float bf2f(unsigned short h) {
  unsigned int u = ((unsigned int)h) << 16;
  return __builtin_bit_cast(float, u);
}

__device__ __forceinline__ int lower_bound_i(const int* __restrict__ arr, int n, int val) {
  int lo = 0, hi = n;
  while (lo < hi) { int mid = (lo + hi) >> 1; if (arr[mid] < val) lo = mid + 1; else hi = mid; }
  return lo;
}

// k_init block-role boundaries (exclusive ends)
#define E_ATOMS 4096
#define E_SP    (E_ATOMS + 128)   // sum_proto
#define E_WL    (E_SP + 8)        // wl
#define E_PR    (E_WL + 128)      // proton normalize
#define E_HZ    (E_PR + 128)      // hin zero
#define E_ES    (E_HZ + 512)      // emb split: 2048*256 elems (zeros past 2001 rows)
#define E_MS    (E_ES + 192)      // mw^T split (768*256)

__global__ __launch_bounds__(256) void k_init(
    const float* __restrict__ hctx, const float* __restrict__ pos, const int* __restrict__ ab,
    const float* __restrict__ pcnt, const float* __restrict__ proto,
    const float* __restrict__ emb, const float* __restrict__ mw,
    float* __restrict__ nh, float* __restrict__ center, float* __restrict__ inv_sp,
    float* __restrict__ wl, float* __restrict__ pnT, float* __restrict__ hin,
    unsigned short* __restrict__ embH, unsigned short* __restrict__ embL,
    unsigned short* __restrict__ mwTH, unsigned short* __restrict__ mwTL) {
  int blk = blockIdx.x, t = threadIdx.x;
  __shared__ float red[256];
  if (blk < E_ATOMS) {
    int b = blk;
    int s = lower_bound_i(ab, NATOMS, b);
    int e = lower_bound_i(ab, NATOMS, b + 1);
    // 4-wide independent accumulation (break the dependent load-add chain)
    float a0 = 0.f, a1 = 0.f, a2 = 0.f, a3 = 0.f;
    int a = s;
    for (; a + 3 < e; a += 4) {
      a0 += hctx[(size_t)(a + 0) * HD + t];
      a1 += hctx[(size_t)(a + 1) * HD + t];
      a2 += hctx[(size_t)(a + 2) * HD + t];
      a3 += hctx[(size_t)(a + 3) * HD + t];
    }
    for (; a < e; ++a) a0 += hctx[(size_t)a * HD + t];
    nh[(size_t)b * HD + t] = (a0 + a1) + (a2 + a3);
    if (t < 3) {
      float ps = 0.f;
      for (int aa = s; aa < e; ++aa) ps += pos[aa * 3 + t];
      center[b * 3 + t] = ps / fmaxf((float)(e - s), 1.0f);
    }
  } else if (blk < E_SP) {
    int p = blk - E_ATOMS;
    float s = 0.f;
    for (int v = t; v < NV; v += 256) s += pcnt[(size_t)p * NV + v];
    red[t] = s; __syncthreads();
    for (int off = 128; off; off >>= 1) { if (t < off) red[t] += red[t + off]; __syncthreads(); }
    if (!t) inv_sp[p] = 1.0f / (red[0] + 1.0f);
  } else if (blk < E_WL) {
    int v = (blk - E_SP) * 256 + t;
    if (v < NV) {
      float sm = 0.f;
      for (int p = 0; p < NP; ++p) sm += (pcnt[(size_t)p * NV + v] > 0.f) ? 1.f : 0.f;
      wl[v] = logf((1.0f + NP) / (1.0f + sm)) + 1.0f;
    }
  } else if (blk < E_PR) {
    int p = blk - E_WL;
    float x = proto[p * HD + t];
    red[t] = x * x; __syncthreads();
    for (int off = 128; off; off >>= 1) { if (t < off) red[t] += red[t + off]; __syncthreads(); }
    float inv = 1.0f / fmaxf(sqrtf(red[0]), 1e-12f);
    pnT[t * NP + p] = x * inv;
  } else if (blk < E_HZ) {
    hin[(blk - E_PR) * 256 + t] = 0.f;
  } else if (blk < E_ES) {
    int e0 = ((blk - E_HZ) * 256 + t) * 4;  // covers 2048*256 exactly
#pragma unroll
    for (int j = 0; j < 4; ++j) {
      int e = e0 + j;
      if (e < 2001 * HD) {
        float x = emb[e];
        unsigned short h = f2bf(x);
        embH[e] = h; embL[e] = f2bf(x - bf2f(h));
      } else {
        embH[e] = 0; embL[e] = 0;  // pad rows 2001..2047 -> zeros
      }
    }
  } else {
    int e0 = ((blk - E_ES) * 256 + t) * 4;  // 768*256 exact
#pragma unroll
    for (int j = 0; j < 4; ++j) {
      int e = e0 + j;
      int n = e / 768, k = e - n * 768;     // mwT[n][k] = mw[k][n]
      float x = mw[(size_t)k * HD + n];
      unsigned short h = f2bf(x);
      mwTH[e] = h; mwTL[e] = f2bf(x - bf2f(h));
    }
  }
}

// Fused: residue masked segsum (LDS compaction, 8-wide latency-hiding accumulate)
// -> l2norm -> cos -> top4 -> hin scatter. Blocks [NB, NB+2048): bemb split-K atomic.
__global__ __launch_bounds__(256) void k_res_topk_bemb(
    const float* __restrict__ hres, const float* __restrict__ rpos,
    const int* __restrict__ rb, const float* __restrict__ center,
    const float* __restrict__ pcnt, const float* __restrict__ wl,
    const float* __restrict__ inv_sp, const float* __restrict__ emb,
    const float* __restrict__ pnT, int* __restrict__ knn, float* __restrict__ hin) {
  int blk = blockIdx.x, t = threadIdx.x;
  __shared__ int lst[256];
  __shared__ int cnt;
  __shared__ float cw[VCHUNK];
  __shared__ float sre[HD];
  __shared__ float part[256];
  __shared__ float c[NP];
  __shared__ float rv[256];
  __shared__ int ri[256];
  __shared__ int kk[4];
  if (blk < NB) {
    int b = blk;
    int s = lower_bound_i(rb, NRES, b);
    int e = lower_bound_i(rb, NRES, b + 1);
    float c0 = center[b * 3], c1 = center[b * 3 + 1], c2 = center[b * 3 + 2];
    float a0 = 0.f, a1 = 0.f, a2 = 0.f, a3 = 0.f, a4 = 0.f, a5 = 0.f, a6 = 0.f, a7 = 0.f;
    for (int cc = s; cc < e; cc += 256) {
      if (!t) cnt = 0;
      __syncthreads();
      int r = cc + t;
      if (r < e) {
        float dx = rpos[(size_t)r * 9 + 3] - c0;
        float dy = rpos[(size_t)r * 9 + 4] - c1;
        float dz = rpos[(size_t)r * 9 + 5] - c2;
        if (dx * dx + dy * dy + dz * dz < 36.0f) {
          int j = atomicAdd(&cnt, 1);
          lst[j] = r;
        }
      }
      __syncthreads();
      int n = cnt;
      int j = 0;
      // 8 independent accumulators -> 8 outstanding loads instead of a serial chain
      for (; j + 7 < n; j += 8) {
        a0 += hres[(size_t)lst[j + 0] * HD + t];
        a1 += hres[(size_t)lst[j + 1] * HD + t];
        a2 += hres[(size_t)lst[j + 2] * HD + t];
        a3 += hres[(size_t)lst[j + 3] * HD + t];
        a4 += hres[(size_t)lst[j + 4] * HD + t];
        a5 += hres[(size_t)lst[j + 5] * HD + t];
        a6 += hres[(size_t)lst[j + 6] * HD + t];
        a7 += hres[(size_t)lst[j + 7] * HD + t];
      }
      for (; j < n; ++j) a0 += hres[(size_t)lst[j] * HD + t];
      __syncthreads();
    }
    float acc = ((a0 + a1) + (a2 + a3)) + ((a4 + a5) + (a6 + a7));
    // ---- fused costopk (re row lives in LDS only) ----
    sre[t] = acc;
    part[t] = acc * acc;
    __syncthreads();
    for (int off = 128; off; off >>= 1) { if (t < off) part[t] += part[t + off]; __syncthreads(); }
    float invn = 1.0f / fmaxf(sqrtf(part[0]), 1e-12f);
    __syncthreads();
    int p = t & 127, half = t >> 7;
    float d = 0.f;
    int h0 = half * 128;
#pragma unroll 8
    for (int h = h0; h < h0 + 128; ++h) d += sre[h] * pnT[h * NP + p];
    part[t] = d;
    __syncthreads();
    if (t < NP) c[t] = (part[t] + part[t + 128]) * invn;
    __syncthreads();
    for (int k = 0; k < 4; ++k) {
      rv[t] = (t < NP) ? c[t] : -INFINITY;
      ri[t] = t;
      __syncthreads();
      for (int off = 128; off; off >>= 1) {
        if (t < off) {
          float ov = rv[t + off]; int oi = ri[t + off];
          if (ov > rv[t] || (ov == rv[t] && oi < ri[t])) { rv[t] = ov; ri[t] = oi; }
        }
        __syncthreads();
      }
      if (!t) { knn[b * 4 + k] = ri[0]; kk[k] = ri[0]; }
      if (t == ri[0]) c[t] = -INFINITY;
      __syncthreads();
    }
#pragma unroll
    for (int k = 0; k < 4; ++k) atomicAdd(&hin[kk[k] * HD + t], sre[t]);
  } else {
    int pc = blk - NB;
    int p = pc >> 4, ch = pc & 15;
    int v0 = ch * VCHUNK;
    float isp = inv_sp[p];
    for (int v = t; v < VCHUNK; v += 256) cw[v] = pcnt[(size_t)p * NV + v0 + v] * wl[v0 + v] * isp;
    __syncthreads();
    float acc = 0.f;
#pragma unroll 8
    for (int v = 0; v < VCHUNK; ++v) acc += cw[v] * emb[(size_t)(v0 + v) * HD + t];
    atomicAdd(&hin[p * HD + t], acc);
  }
}

// hw[p] = (relu(hin[p] @ w1)) @ w2
__global__ __launch_bounds__(256) void k_h1hw(const float* __restrict__ hin,
                                              const float* __restrict__ w1,
                                              const float* __restrict__ w2,
                                              float* __restrict__ hw) {
  int p = blockIdx.x, t = threadIdx.x;
  __shared__ float s[HD], s2[HD];
  s[t] = hin[p * HD + t];
  __syncthreads();
  float a = 0.f;
#pragma unroll 8
  for (int h = 0; h < HD; ++h) a += s[h] * w1[h * HD + t];
  s2[t] = fmaxf(a, 0.f);
  __syncthreads();
  float o = 0.f;
#pragma unroll 8
  for (int h = 0; h < HD; ++h) o += s2[h] * w2[h * HD + t];
  hw[p * HD + t] = o;
}

// GEMM1: tb = U @ mw + mb; U built on the fly. 64x64 tile, 512 threads (8 waves, 2Mx4N).
__global__ __launch_bounds__(512) void k_gemm1(
    const float* __restrict__ nh, const float* __restrict__ emb,
    const int* __restrict__ wid, const int* __restrict__ knn, const float* __restrict__ hw,
    const unsigned short* __restrict__ mwTH, const unsigned short* __restrict__ mwTL,
    const float* __restrict__ mb,
    unsigned short* __restrict__ tbH, unsigned short* __restrict__ tbL) {
  __shared__ __align__(16) unsigned short Ah[64][40], Al[64][40], Bh[64][40], Bl[64][40];
  __shared__ int swid[64];
  __shared__ int4 sknn[64];
  int tid = threadIdx.x, lane = tid & 63, w = tid >> 6;  // w in 0..7
  int wm = (w & 1) * 32, wn = (w >> 1) * 16;
  int bm = blockIdx.x * 64, bn = blockIdx.y * 64;
  if (tid < 64) { swid[tid] = wid[bm + tid]; sknn[tid] = ((const int4*)knn)[bm + tid]; }
  f32x4 acc[2] = {};
  for (int k0 = 0; k0 < 768; k0 += 32) {
    __syncthreads();
    for (int i = tid; i < 2048; i += 512) {
      int m = i >> 5, k = i & 31;
      float x;
      if (k0 < 256) {
        x = 0.8f * nh[(size_t)(bm + m) * HD + k0 + k];
      } else if (k0 < 512) {
        x = 0.7f * emb[(size_t)swid[m] * HD + (k0 - 256) + k];
      } else {
        int4 kn = sknn[m];
        int kk2 = (k0 - 512) + k;
        x = 1.5f * (hw[kn.x * HD + kk2] + hw[kn.y * HD + kk2] +
                    hw[kn.z * HD + kk2] + hw[kn.w * HD + kk2]);
      }
      unsigned short h = f2bf(x);
      Ah[m][k] = h; Al[m][k] = f2bf(x - bf2f(h));
    }
    if (tid < 256) {  // B: 2048 elems as 256 u16x8
      int e = tid * 8, n = e >> 5, k = e & 31;
      size_t idx = (size_t)(bn + n) * 768 + k0 + k;
      *(u16x8*)&Bh[n][k] = *(const u16x8*)&mwTH[idx];
      *(u16x8*)&Bl[n][k] = *(const u16x8*)&mwTL[idx];
    }
    __syncthreads();
    int r = lane & 15, kb = (lane >> 4) * 8;
    bf16x8 bh = *(const bf16x8*)&Bh[wn + r][kb];
    bf16x8 bl = *(const bf16x8*)&Bl[wn + r][kb];
#pragma unroll
    for (int i = 0; i < 2; ++i) {
      bf16x8 ah = *(const bf16x8*)&Ah[wm + i * 16 + r][kb];
      bf16x8 al = *(const bf16x8*)&Al[wm + i * 16 + r][kb];
      acc[i] = __builtin_amdgcn_mfma_f32_16x16x32_bf16(ah, bh, acc[i], 0, 0, 0);
      acc[i] = __builtin_amdgcn_mfma_f32_16x16x32_bf16(ah, bl, acc[i], 0, 0, 0);
      acc[i] = __builtin_amdgcn_mfma_f32_16x16x32_bf16(al, bh, acc[i], 0, 0, 0);
    }
  }
  int col0 = lane & 15, row0 = (lane >> 4) * 4;
  int col = bn + wn + col0;
  float bv = mb[col];
#pragma unroll
  for (int i = 0; i < 2; ++i)
#pragma unroll
    for (int rr = 0; rr < 4; ++rr) {
      int row = bm + wm + i * 16 + row0 + rr;
      float x = acc[i][rr] + bv;
      unsigned short h = f2bf(x);
      tbH[(size_t)row * HD + col] = h;
      tbL[(size_t)row * HD + col] = f2bf(x - bf2f(h));
    }
}

// GEMM2: out = tb @ emb^T. 128x128 tile, 4 waves (2x2 of 64x64), padded LDS, ushort8 staging.
__global__ __launch_bounds__(256) void k_gemm2(
    const unsigned short* __restrict__ tbH, const unsigned short* __restrict__ tbL,
    const unsigned short* __restrict__ embH, const unsigned short* __restrict__ embL,
    float* __restrict__ out) {
  __shared__ __align__(16) unsigned short AH[128][40], AL[128][40], BH[128][40], BL[128][40];
  int tid = threadIdx.x, lane = tid & 63, w = tid >> 6;
  int wm = (w & 1) * 64, wn = (w >> 1) * 64;
  int bm = blockIdx.x * 128, bn = blockIdx.y * 128;
  f32x4 acc[4][4] = {};
  for (int k0 = 0; k0 < HD; k0 += 32) {
    __syncthreads();
#pragma unroll
    for (int cch = 0; cch < 2; ++cch) {
      int e = (tid + cch * 256) * 8;  // 0..4088
      int m = e >> 5, k = e & 31;
      *(u16x8*)&AH[m][k] = *(const u16x8*)&tbH[(size_t)(bm + m) * HD + k0 + k];
      *(u16x8*)&AL[m][k] = *(const u16x8*)&tbL[(size_t)(bm + m) * HD + k0 + k];
      *(u16x8*)&BH[m][k] = *(const u16x8*)&embH[(size_t)(bn + m) * HD + k0 + k];
      *(u16x8*)&BL[m][k] = *(const u16x8*)&embL[(size_t)(bn + m) * HD + k0 + k];
    }
    __syncthreads();
    int r = lane & 15, kb = (lane >> 4) * 8;
    bf16x8 ah[4], al[4], bh[4], bl[4];
#pragma unroll
    for (int i = 0; i < 4; ++i) {
      ah[i] = *(const bf16x8*)&AH[wm + i * 16 + r][kb];
      al[i] = *(const bf16x8*)&AL[wm + i * 16 + r][kb];
      bh[i] = *(const bf16x8*)&BH[wn + i * 16 + r][kb];
      bl[i] = *(const bf16x8*)&BL[wn + i * 16 + r][kb];
    }
#pragma unroll
    for (int i = 0; i < 4; ++i)
#pragma unroll
      for (int j = 0; j < 4; ++j) {
        acc[i][j] = __builtin_amdgcn_mfma_f32_16x16x32_bf16(ah[i], bh[j], acc[i][j], 0, 0, 0);
        acc[i][j] = __builtin_amdgcn_mfma_f32_16x16x32_bf16(ah[i], bl[j], acc[i][j], 0, 0, 0);
        acc[i][j] = __builtin_amdgcn_mfma_f32_16x16x32_bf16(al[i], bh[j], acc[i][j], 0, 0, 0);
      }
  }
  int col0 = lane & 15, row0 = (lane >> 4) * 4;
#pragma unroll
  for (int i = 0; i < 4; ++i)
#pragma unroll
    for (int j = 0; j < 4; ++j) {
      int col = bn + wn + j * 16 + col0;
      if (col <= 2000) {
#pragma unroll
        for (int rr = 0; rr < 4; ++rr) {
          int row = bm + wm + i * 16 + row0 + rr;
          out[(size_t)row * 2001 + col] = acc[i][j][rr];
        }
      }
    }
}

extern "C" void kernel_launch(void* const* d_in, const int* in_sizes, int n_in,
                              void* d_out, int out_size, void* d_ws, size_t ws_size,
                              hipStream_t stream) {
  const float* hctx  = (const float*)d_in[0];
  const float* pos   = (const float*)d_in[1];
  const float* hres  = (const float*)d_in[2];
  const float* rpos  = (const float*)d_in[3];
  const float* emb   = (const float*)d_in[4];
  const float* proto = (const float*)d_in[5];
  const float* pcnt  = (const float*)d_in[6];
  const float* mw    = (const float*)d_in[7];
  const float* mb    = (const float*)d_in[8];
  const float* w1    = (const float*)d_in[9];
  const float* w2    = (const float*)d_in[10];
  const int* wid     = (const int*)d_in[11];
  const int* ab      = (const int*)d_in[12];
  const int* rb      = (const int*)d_in[13];
  float* out = (float*)d_out;

  float* ws     = (float*)d_ws;
  float* nh     = ws;                            // NB*HD
  float* center = nh + (size_t)NB * HD;          // NB*4
  float* inv_sp = center + (size_t)NB * 4;       // 128
  float* wl     = inv_sp + 128;                  // 2048 (2000 used)
  float* pnT    = wl + 2048;                     // HD*NP
  float* hin    = pnT + NP * HD;                 // NP*HD
  float* hw     = hin + NP * HD;                 // NP*HD
  int*   knn    = (int*)(hw + NP * HD);          // NB*4 ints
  unsigned short* tbH  = (unsigned short*)(knn + NB * 4);   // NB*HD
  unsigned short* tbL  = tbH + (size_t)NB * HD;
  unsigned short* embH = tbL + (size_t)NB * HD;             // 2048*HD (rows >=2001 zeroed)
  unsigned short* embL = embH + (size_t)2048 * HD;
  unsigned short* mwTH = embL + (size_t)2048 * HD;          // 768*HD (transposed)
  unsigned short* mwTL = mwTH + (size_t)768 * HD;

  k_init<<<E_MS, 256, 0, stream>>>(hctx, pos, ab, pcnt, proto, emb, mw,
                                   nh, center, inv_sp, wl, pnT, hin,
                                   embH, embL, mwTH, mwTL);
  k_res_topk_bemb<<<NB + NP * 16, 256, 0, stream>>>(hres, rpos, rb, center,
                                                    pcnt, wl, inv_sp, emb, pnT, knn, hin);
  k_h1hw<<<NP, 256, 0, stream>>>(hin, w1, w2, hw);
  k_gemm1<<<dim3(NB / 64, 4), 512, 0, stream>>>(nh, emb, wid, knn, hw,
                                                mwTH, mwTL, mb, tbH, tbL);
  k_gemm2<<<dim3(NB / 128, 16), 256, 0, stream>>>(tbH, tbL, embH, embL, out);
}

// Round 11
// 534.933 us; speedup vs baseline: 2.5692x; 1.0253x over previous
//
#include <hip/hip_runtime.h>
#include <hip/hip_bf16.h>
#include <math.h>

#define NB 4096
#define HD 256
#define NP 128
#define NV 2000
#define NATOMS 32768
#define NRES 262144
#define VCHUNK 125  // 2000 = 16 * 125

typedef __attribute__((ext_vector_type(8))) short bf16x8;
typedef __attribute__((ext_vector_type(4))) float f32x4;
typedef __attribute__((ext_vector_type(8))) unsigned short u16x8;

__device__ __forceinline__ unsigned short f2bf(float f) {
  unsigned int u = __builtin_bit_cast(unsigned int, f);
  u += 0x7FFFu + ((u >> 16) & 1u);  // RNE
  return (unsigned short)(u >> 16);
}
__device__ __forceinline__ float bf2f(unsigned short h) {
  unsigned int u = ((unsigned int)h) << 16;
  return __builtin_bit_cast(float, u);
}

// k_init0 block-role boundaries (exclusive ends)
#define I_SP   128             // sumproto
#define I_WL   (I_SP + 8)      // wl
#define I_PR   (I_WL + 128)    // proton normalize
#define I_HZ   (I_PR + 128)    // hin zero
#define I_ES   (I_HZ + 512)    // emb split (2048*256, zero-pad rows >= 2001)
#define I_MS   (I_ES + 192)    // mw^T split (768*256)
#define I_AS   (I_MS + 128)    // ab segment starts (32768)
#define I_RS   (I_AS + 1024)   // rb segment starts (262144)

// Prep: sumproto + wl + proton + hin=0 + emb/mw splits + segment-start scans
__global__ __launch_bounds__(256) void k_init0(
    const int* __restrict__ ab, const int* __restrict__ rb,
    const float* __restrict__ pcnt, const float* __restrict__ proto,
    const float* __restrict__ emb, const float* __restrict__ mw,
    float* __restrict__ inv_sp, float* __restrict__ wl, float* __restrict__ pnT,
    float* __restrict__ hin,
    unsigned short* __restrict__ embH, unsigned short* __restrict__ embL,
    unsigned short* __restrict__ mwTH, unsigned short* __restrict__ mwTL,
    int* __restrict__ astart, int* __restrict__ rstart) {
  int blk = blockIdx.x, t = threadIdx.x;
  __shared__ float red[256];
  if (blk < I_SP) {
    int p = blk;
    float s = 0.f;
    for (int v = t; v < NV; v += 256) s += pcnt[(size_t)p * NV + v];
    red[t] = s; __syncthreads();
    for (int off = 128; off; off >>= 1) { if (t < off) red[t] += red[t + off]; __syncthreads(); }
    if (!t) inv_sp[p] = 1.0f / (red[0] + 1.0f);
  } else if (blk < I_WL) {
    int v = (blk - I_SP) * 256 + t;
    if (v < NV) {
      float sm = 0.f;
      for (int p = 0; p < NP; ++p) sm += (pcnt[(size_t)p * NV + v] > 0.f) ? 1.f : 0.f;
      wl[v] = logf((1.0f + NP) / (1.0f + sm)) + 1.0f;
    }
  } else if (blk < I_PR) {
    int p = blk - I_WL;
    float x = proto[p * HD + t];
    red[t] = x * x; __syncthreads();
    for (int off = 128; off; off >>= 1) { if (t < off) red[t] += red[t + off]; __syncthreads(); }
    float inv = 1.0f / fmaxf(sqrtf(red[0]), 1e-12f);
    pnT[t * NP + p] = x * inv;
  } else if (blk < I_HZ) {
    hin[(blk - I_PR) * 256 + t] = 0.f;
  } else if (blk < I_ES) {
    int e0 = ((blk - I_HZ) * 256 + t) * 4;  // covers 2048*256 exactly
#pragma unroll
    for (int j = 0; j < 4; ++j) {
      int e = e0 + j;
      if (e < 2001 * HD) {
        float x = emb[e];
        unsigned short h = f2bf(x);
        embH[e] = h; embL[e] = f2bf(x - bf2f(h));
      } else {
        embH[e] = 0; embL[e] = 0;
      }
    }
  } else if (blk < I_MS) {
    int e0 = ((blk - I_ES) * 256 + t) * 4;  // 768*256 exact
#pragma unroll
    for (int j = 0; j < 4; ++j) {
      int e = e0 + j;
      int n = e / 768, k = e - n * 768;     // mwT[n][k] = mw[k][n]
      float x = mw[(size_t)k * HD + n];
      unsigned short h = f2bf(x);
      mwTH[e] = h; mwTL[e] = f2bf(x - bf2f(h));
    }
  } else if (blk < I_AS) {
    int i = (blk - I_MS) * 256 + t;  // 0..32767
    int cur = ab[i];
    int prev = (i == 0) ? -1 : ab[i - 1];
    for (int b = prev + 1; b <= cur; ++b) astart[b] = i;
    if (i == NATOMS - 1)
      for (int b = cur + 1; b <= NB; ++b) astart[b] = NATOMS;
  } else {
    int i = (blk - I_AS) * 256 + t;  // 0..262143
    int cur = rb[i];
    int prev = (i == 0) ? -1 : rb[i - 1];
    for (int b = prev + 1; b <= cur; ++b) rstart[b] = i;
    if (i == NRES - 1)
      for (int b = cur + 1; b <= NB; ++b) rstart[b] = NRES;
  }
}

// Mega: per-batch atoms segsum (center in LDS) -> residue masked segsum (compaction)
// -> l2norm -> cos -> top4 -> hin scatter.  Blocks [NB, NB+2048): bemb split-K atomic.
__global__ __launch_bounds__(256) void k_mega(
    const float* __restrict__ hctx, const float* __restrict__ pos,
    const float* __restrict__ hres, const float* __restrict__ rpos,
    const int* __restrict__ astart, const int* __restrict__ rstart,
    const float* __restrict__ pcnt, const float* __restrict__ wl,
    const float* __restrict__ inv_sp, const float* __restrict__ emb,
    const float* __restrict__ pnT,
    float* __restrict__ nh, int* __restrict__ knn, float* __restrict__ hin) {
  int blk = blockIdx.x, t = threadIdx.x;
  __shared__ int lst[256];
  __shared__ int cnt;
  __shared__ float cw[VCHUNK];
  __shared__ float sre[HD];
  __shared__ float part[256];
  __shared__ float c[NP];
  __shared__ float rv[256];
  __shared__ int ri[256];
  __shared__ int kk[4];
  __shared__ float scen[3];
  if (blk < NB) {
    int b = blk;
    // ---- atoms segment sum (no search: precomputed starts) ----
    int s = astart[b], e = astart[b + 1];
    {
      float a0 = 0.f, a1 = 0.f, a2 = 0.f, a3 = 0.f;
      int a = s;
      for (; a + 3 < e; a += 4) {
        a0 += hctx[(size_t)(a + 0) * HD + t];
        a1 += hctx[(size_t)(a + 1) * HD + t];
        a2 += hctx[(size_t)(a + 2) * HD + t];
        a3 += hctx[(size_t)(a + 3) * HD + t];
      }
      for (; a < e; ++a) a0 += hctx[(size_t)a * HD + t];
      nh[(size_t)b * HD + t] = (a0 + a1) + (a2 + a3);
      if (t < 3) {
        float ps = 0.f;
        for (int aa = s; aa < e; ++aa) ps += pos[aa * 3 + t];
        scen[t] = ps / fmaxf((float)(e - s), 1.0f);
      }
    }
    __syncthreads();
    float c0 = scen[0], c1 = scen[1], c2 = scen[2];
    // ---- residue masked segment sum ----
    int rs = rstart[b], re_ = rstart[b + 1];
    float a0 = 0.f, a1 = 0.f, a2 = 0.f, a3 = 0.f, a4 = 0.f, a5 = 0.f, a6 = 0.f, a7 = 0.f;
    for (int cc = rs; cc < re_; cc += 256) {
      if (!t) cnt = 0;
      __syncthreads();
      int r = cc + t;
      if (r < re_) {
        float dx = rpos[(size_t)r * 9 + 3] - c0;
        float dy = rpos[(size_t)r * 9 + 4] - c1;
        float dz = rpos[(size_t)r * 9 + 5] - c2;
        if (dx * dx + dy * dy + dz * dz < 36.0f) {
          int j = atomicAdd(&cnt, 1);
          lst[j] = r;
        }
      }
      __syncthreads();
      int n = cnt;
      int j = 0;
      for (; j + 7 < n; j += 8) {
        a0 += hres[(size_t)lst[j + 0] * HD + t];
        a1 += hres[(size_t)lst[j + 1] * HD + t];
        a2 += hres[(size_t)lst[j + 2] * HD + t];
        a3 += hres[(size_t)lst[j + 3] * HD + t];
        a4 += hres[(size_t)lst[j + 4] * HD + t];
        a5 += hres[(size_t)lst[j + 5] * HD + t];
        a6 += hres[(size_t)lst[j + 6] * HD + t];
        a7 += hres[(size_t)lst[j + 7] * HD + t];
      }
      for (; j < n; ++j) a0 += hres[(size_t)lst[j] * HD + t];
      __syncthreads();
    }
    float acc = ((a0 + a1) + (a2 + a3)) + ((a4 + a5) + (a6 + a7));
    // ---- fused costopk ----
    sre[t] = acc;
    part[t] = acc * acc;
    __syncthreads();
    for (int off = 128; off; off >>= 1) { if (t < off) part[t] += part[t + off]; __syncthreads(); }
    float invn = 1.0f / fmaxf(sqrtf(part[0]), 1e-12f);
    __syncthreads();
    int p = t & 127, half = t >> 7;
    float d = 0.f;
    int h0 = half * 128;
#pragma unroll 8
    for (int h = h0; h < h0 + 128; ++h) d += sre[h] * pnT[h * NP + p];
    part[t] = d;
    __syncthreads();
    if (t < NP) c[t] = (part[t] + part[t + 128]) * invn;
    __syncthreads();
    for (int k = 0; k < 4; ++k) {
      rv[t] = (t < NP) ? c[t] : -INFINITY;
      ri[t] = t;
      __syncthreads();
      for (int off = 128; off; off >>= 1) {
        if (t < off) {
          float ov = rv[t + off]; int oi = ri[t + off];
          if (ov > rv[t] || (ov == rv[t] && oi < ri[t])) { rv[t] = ov; ri[t] = oi; }
        }
        __syncthreads();
      }
      if (!t) { knn[b * 4 + k] = ri[0]; kk[k] = ri[0]; }
      if (t == ri[0]) c[t] = -INFINITY;
      __syncthreads();
    }
#pragma unroll
    for (int k = 0; k < 4; ++k) atomicAdd(&hin[kk[k] * HD + t], sre[t]);
  } else {
    int pc = blk - NB;
    int p = pc >> 4, ch = pc & 15;
    int v0 = ch * VCHUNK;
    float isp = inv_sp[p];
    for (int v = t; v < VCHUNK; v += 256) cw[v] = pcnt[(size_t)p * NV + v0 + v] * wl[v0 + v] * isp;
    __syncthreads();
    float acc = 0.f;
#pragma unroll 8
    for (int v = 0; v < VCHUNK; ++v) acc += cw[v] * emb[(size_t)(v0 + v) * HD + t];
    atomicAdd(&hin[p * HD + t], acc);
  }
}

// hw[p] = (relu(hin[p] @ w1)) @ w2
__global__ __launch_bounds__(256) void k_h1hw(const float* __restrict__ hin,
                                              const float* __restrict__ w1,
                                              const float* __restrict__ w2,
                                              float* __restrict__ hw) {
  int p = blockIdx.x, t = threadIdx.x;
  __shared__ float s[HD], s2[HD];
  s[t] = hin[p * HD + t];
  __syncthreads();
  float a = 0.f;
#pragma unroll 8
  for (int h = 0; h < HD; ++h) a += s[h] * w1[h * HD + t];
  s2[t] = fmaxf(a, 0.f);
  __syncthreads();
  float o = 0.f;
#pragma unroll 8
  for (int h = 0; h < HD; ++h) o += s2[h] * w2[h * HD + t];
  hw[p * HD + t] = o;
}

// GEMM1: tb = U @ mw + mb; U built on the fly. 64x64 tile, 512 threads (8 waves, 2Mx4N).
__global__ __launch_bounds__(512) void k_gemm1(
    const float* __restrict__ nh, const float* __restrict__ emb,
    const int* __restrict__ wid, const int* __restrict__ knn, const float* __restrict__ hw,
    const unsigned short* __restrict__ mwTH, const unsigned short* __restrict__ mwTL,
    const float* __restrict__ mb,
    unsigned short* __restrict__ tbH, unsigned short* __restrict__ tbL) {
  __shared__ __align__(16) unsigned short Ah[64][40], Al[64][40], Bh[64][40], Bl[64][40];
  __shared__ int swid[64];
  __shared__ int4 sknn[64];
  int tid = threadIdx.x, lane = tid & 63, w = tid >> 6;  // w in 0..7
  int wm = (w & 1) * 32, wn = (w >> 1) * 16;
  int bm = blockIdx.x * 64, bn = blockIdx.y * 64;
  if (tid < 64) { swid[tid] = wid[bm + tid]; sknn[tid] = ((const int4*)knn)[bm + tid]; }
  f32x4 acc[2] = {};
  for (int k0 = 0; k0 < 768; k0 += 32) {
    __syncthreads();
    for (int i = tid; i < 2048; i += 512) {
      int m = i >> 5, k = i & 31;
      float x;
      if (k0 < 256) {
        x = 0.8f * nh[(size_t)(bm + m) * HD + k0 + k];
      } else if (k0 < 512) {
        x = 0.7f * emb[(size_t)swid[m] * HD + (k0 - 256) + k];
      } else {
        int4 kn = sknn[m];
        int kk2 = (k0 - 512) + k;
        x = 1.5f * (hw[kn.x * HD + kk2] + hw[kn.y * HD + kk2] +
                    hw[kn.z * HD + kk2] + hw[kn.w * HD + kk2]);
      }
      unsigned short h = f2bf(x);
      Ah[m][k] = h; Al[m][k] = f2bf(x - bf2f(h));
    }
    if (tid < 256) {  // B: 2048 elems as 256 u16x8
      int e = tid * 8, n = e >> 5, k = e & 31;
      size_t idx = (size_t)(bn + n) * 768 + k0 + k;
      *(u16x8*)&Bh[n][k] = *(const u16x8*)&mwTH[idx];
      *(u16x8*)&Bl[n][k] = *(const u16x8*)&mwTL[idx];
    }
    __syncthreads();
    int r = lane & 15, kb = (lane >> 4) * 8;
    bf16x8 bh = *(const bf16x8*)&Bh[wn + r][kb];
    bf16x8 bl = *(const bf16x8*)&Bl[wn + r][kb];
#pragma unroll
    for (int i = 0; i < 2; ++i) {
      bf16x8 ah = *(const bf16x8*)&Ah[wm + i * 16 + r][kb];
      bf16x8 al = *(const bf16x8*)&Al[wm + i * 16 + r][kb];
      acc[i] = __builtin_amdgcn_mfma_f32_16x16x32_bf16(ah, bh, acc[i], 0, 0, 0);
      acc[i] = __builtin_amdgcn_mfma_f32_16x16x32_bf16(ah, bl, acc[i], 0, 0, 0);
      acc[i] = __builtin_amdgcn_mfma_f32_16x16x32_bf16(al, bh, acc[i], 0, 0, 0);
    }
  }
  int col0 = lane & 15, row0 = (lane >> 4) * 4;
  int col = bn + wn + col0;
  float bv = mb[col];
#pragma unroll
  for (int i = 0; i < 2; ++i)
#pragma unroll
    for (int rr = 0; rr < 4; ++rr) {
      int row = bm + wm + i * 16 + row0 + rr;
      float x = acc[i][rr] + bv;
      unsigned short h = f2bf(x);
      tbH[(size_t)row * HD + col] = h;
      tbL[(size_t)row * HD + col] = f2bf(x - bf2f(h));
    }
}

// GEMM2: out = tb @ emb^T. 128x128 tile, XCD-swizzled 1-D grid (512 blocks).
__global__ __launch_bounds__(256) void k_gemm2(
    const unsigned short* __restrict__ tbH, const unsigned short* __restrict__ tbL,
    const unsigned short* __restrict__ embH, const unsigned short* __restrict__ embL,
    float* __restrict__ out) {
  __shared__ __align__(16) unsigned short AH[128][40], AL[128][40], BH[128][40], BL[128][40];
  int tid = threadIdx.x, lane = tid & 63, w = tid >> 6;
  int wm = (w & 1) * 64, wn = (w >> 1) * 64;
  int orig = blockIdx.x;                       // 512 blocks, 512 % 8 == 0
  int swz = (orig & 7) * 64 + (orig >> 3);     // bijective XCD swizzle
  int bm = (swz & 31) * 128, bn = (swz >> 5) * 128;
  f32x4 acc[4][4] = {};
  for (int k0 = 0; k0 < HD; k0 += 32) {
    __syncthreads();
#pragma unroll
    for (int cch = 0; cch < 2; ++cch) {
      int e = (tid + cch * 256) * 8;  // 0..4088
      int m = e >> 5, k = e & 31;
      *(u16x8*)&AH[m][k] = *(const u16x8*)&tbH[(size_t)(bm + m) * HD + k0 + k];
      *(u16x8*)&AL[m][k] = *(const u16x8*)&tbL[(size_t)(bm + m) * HD + k0 + k];
      *(u16x8*)&BH[m][k] = *(const u16x8*)&embH[(size_t)(bn + m) * HD + k0 + k];
      *(u16x8*)&BL[m][k] = *(const u16x8*)&embL[(size_t)(bn + m) * HD + k0 + k];
    }
    __syncthreads();
    int r = lane & 15, kb = (lane >> 4) * 8;
    bf16x8 ah[4], al[4], bh[4], bl[4];
#pragma unroll
    for (int i = 0; i < 4; ++i) {
      ah[i] = *(const bf16x8*)&AH[wm + i * 16 + r][kb];
      al[i] = *(const bf16x8*)&AL[wm + i * 16 + r][kb];
      bh[i] = *(const bf16x8*)&BH[wn + i * 16 + r][kb];
      bl[i] = *(const bf16x8*)&BL[wn + i * 16 + r][kb];
    }
#pragma unroll
    for (int i = 0; i < 4; ++i)
#pragma unroll
      for (int j = 0; j < 4; ++j) {
        acc[i][j] = __builtin_amdgcn_mfma_f32_16x16x32_bf16(ah[i], bh[j], acc[i][j], 0, 0, 0);
        acc[i][j] = __builtin_amdgcn_mfma_f32_16x16x32_bf16(ah[i], bl[j], acc[i][j], 0, 0, 0);
        acc[i][j] = __builtin_amdgcn_mfma_f32_16x16x32_bf16(al[i], bh[j], acc[i][j], 0, 0, 0);
      }
  }
  int col0 = lane & 15, row0 = (lane >> 4) * 4;
#pragma unroll
  for (int i = 0; i < 4; ++i)
#pragma unroll
    for (int j = 0; j < 4; ++j) {
      int col = bn + wn + j * 16 + col0;
      if (col <= 2000) {
#pragma unroll
        for (int rr = 0; rr < 4; ++rr) {
          int row = bm + wm + i * 16 + row0 + rr;
          out[(size_t)row * 2001 + col] = acc[i][j][rr];
        }
      }
    }
}

extern "C" void kernel_launch(void* const* d_in, const int* in_sizes, int n_in,
                              void* d_out, int out_size, void* d_ws, size_t ws_size,
                              hipStream_t stream) {
  const float* hctx  = (const float*)d_in[0];
  const float* pos   = (const float*)d_in[1];
  const float* hres  = (const float*)d_in[2];
  const float* rpos  = (const float*)d_in[3];
  const float* emb   = (const float*)d_in[4];
  const float* proto = (const float*)d_in[5];
  const float* pcnt  = (const float*)d_in[6];
  const float* mw    = (const float*)d_in[7];
  const float* mb    = (const float*)d_in[8];
  const float* w1    = (const float*)d_in[9];
  const float* w2    = (const float*)d_in[10];
  const int* wid     = (const int*)d_in[11];
  const int* ab      = (const int*)d_in[12];
  const int* rb      = (const int*)d_in[13];
  float* out = (float*)d_out;

  float* ws     = (float*)d_ws;
  float* nh     = ws;                            // NB*HD
  float* inv_sp = nh + (size_t)NB * HD;          // 128
  float* wl     = inv_sp + 128;                  // 2048 (2000 used)
  float* pnT    = wl + 2048;                     // HD*NP
  float* hin    = pnT + NP * HD;                 // NP*HD
  float* hw     = hin + NP * HD;                 // NP*HD
  int*   knn    = (int*)(hw + NP * HD);          // NB*4 ints
  int*   astart = knn + NB * 4;                  // 4104 ints (NB+1 used)
  int*   rstart = astart + 4104;                 // 4104 ints
  unsigned short* tbH  = (unsigned short*)(rstart + 4104);  // NB*HD
  unsigned short* tbL  = tbH + (size_t)NB * HD;
  unsigned short* embH = tbL + (size_t)NB * HD;             // 2048*HD (rows >=2001 zeroed)
  unsigned short* embL = embH + (size_t)2048 * HD;
  unsigned short* mwTH = embL + (size_t)2048 * HD;          // 768*HD (transposed)
  unsigned short* mwTL = mwTH + (size_t)768 * HD;

  k_init0<<<I_RS, 256, 0, stream>>>(ab, rb, pcnt, proto, emb, mw,
                                    inv_sp, wl, pnT, hin,
                                    embH, embL, mwTH, mwTL, astart, rstart);
  k_mega<<<NB + NP * 16, 256, 0, stream>>>(hctx, pos, hres, rpos, astart, rstart,
                                           pcnt, wl, inv_sp, emb, pnT, nh, knn, hin);
  k_h1hw<<<NP, 256, 0, stream>>>(hin, w1, w2, hw);
  k_gemm1<<<dim3(NB / 64, 4), 512, 0, stream>>>(nh, emb, wid, knn, hw,
                                                mwTH, mwTL, mb, tbH, tbL);
  k_gemm2<<<512, 256, 0, stream>>>(tbH, tbL, embH, embL, out);
}

// Round 12
// 513.938 us; speedup vs baseline: 2.6742x; 1.0409x over previous
//
#include <hip/hip_runtime.h>
#include <hip/hip_bf16.h>
#include <math.h>

#define NB 4096
#define HD 256
#define NP 128
#define NV 2000
#define NATOMS 32768
#define NRES 262144
#define VCHUNK 125  // 2000 = 16 * 125

typedef __attribute__((ext_vector_type(8))) short bf16x8;
typedef __attribute__((ext_vector_type(4))) float f32x4;
typedef __attribute__((ext_vector_type(8))) unsigned short u16x8;

__device__ __forceinline__ unsigned short f2bf(float f) {
  unsigned int u = __builtin_bit_cast(unsigned int, f);
  u += 0x7FFFu + ((u >> 16) & 1u);  // RNE
  return (unsigned short)(u >> 16);
}
__device__ __forceinline__ float bf2f(unsigned short h) {
  unsigned int u = ((unsigned int)h) << 16;
  return __builtin_bit_cast(float, u);
}

// k_init0 block-role boundaries (exclusive ends)
#define I_SP   128             // sumproto
#define I_WL   (I_SP + 8)      // wl
#define I_PR   (I_WL + 128)    // proton normalize
#define I_HZ   (I_PR + 128)    // hin zero
#define I_ES   (I_HZ + 512)    // emb split (2048*256, zero-pad rows >= 2001)
#define I_MS   (I_ES + 192)    // mw^T split (768*256)
#define I_AS   (I_MS + 128)    // ab segment starts (32768)
#define I_RS   (I_AS + 1024)   // rb segment starts (262144)

__global__ __launch_bounds__(256) void k_init0(
    const int* __restrict__ ab, const int* __restrict__ rb,
    const float* __restrict__ pcnt, const float* __restrict__ proto,
    const float* __restrict__ emb, const float* __restrict__ mw,
    float* __restrict__ inv_sp, float* __restrict__ wl, float* __restrict__ pnT,
    float* __restrict__ hin,
    unsigned short* __restrict__ embH, unsigned short* __restrict__ embL,
    unsigned short* __restrict__ mwTH, unsigned short* __restrict__ mwTL,
    int* __restrict__ astart, int* __restrict__ rstart) {
  int blk = blockIdx.x, t = threadIdx.x;
  __shared__ float red[256];
  if (blk < I_SP) {
    int p = blk;
    float s = 0.f;
    for (int v = t; v < NV; v += 256) s += pcnt[(size_t)p * NV + v];
    red[t] = s; __syncthreads();
    for (int off = 128; off; off >>= 1) { if (t < off) red[t] += red[t + off]; __syncthreads(); }
    if (!t) inv_sp[p] = 1.0f / (red[0] + 1.0f);
  } else if (blk < I_WL) {
    int v = (blk - I_SP) * 256 + t;
    if (v < NV) {
      float sm = 0.f;
      for (int p = 0; p < NP; ++p) sm += (pcnt[(size_t)p * NV + v] > 0.f) ? 1.f : 0.f;
      wl[v] = logf((1.0f + NP) / (1.0f + sm)) + 1.0f;
    }
  } else if (blk < I_PR) {
    int p = blk - I_WL;
    float x = proto[p * HD + t];
    red[t] = x * x; __syncthreads();
    for (int off = 128; off; off >>= 1) { if (t < off) red[t] += red[t + off]; __syncthreads(); }
    float inv = 1.0f / fmaxf(sqrtf(red[0]), 1e-12f);
    pnT[t * NP + p] = x * inv;
  } else if (blk < I_HZ) {
    hin[(blk - I_PR) * 256 + t] = 0.f;
  } else if (blk < I_ES) {
    int e0 = ((blk - I_HZ) * 256 + t) * 4;
#pragma unroll
    for (int j = 0; j < 4; ++j) {
      int e = e0 + j;
      if (e < 2001 * HD) {
        float x = emb[e];
        unsigned short h = f2bf(x);
        embH[e] = h; embL[e] = f2bf(x - bf2f(h));
      } else {
        embH[e] = 0; embL[e] = 0;
      }
    }
  } else if (blk < I_MS) {
    int e0 = ((blk - I_ES) * 256 + t) * 4;
#pragma unroll
    for (int j = 0; j < 4; ++j) {
      int e = e0 + j;
      int n = e / 768, k = e - n * 768;     // mwT[n][k] = mw[k][n]
      float x = mw[(size_t)k * HD + n];
      unsigned short h = f2bf(x);
      mwTH[e] = h; mwTL[e] = f2bf(x - bf2f(h));
    }
  } else if (blk < I_AS) {
    int i = (blk - I_MS) * 256 + t;
    int cur = ab[i];
    int prev = (i == 0) ? -1 : ab[i - 1];
    for (int b = prev + 1; b <= cur; ++b) astart[b] = i;
    if (i == NATOMS - 1)
      for (int b = cur + 1; b <= NB; ++b) astart[b] = NATOMS;
  } else {
    int i = (blk - I_AS) * 256 + t;
    int cur = rb[i];
    int prev = (i == 0) ? -1 : rb[i - 1];
    for (int b = prev + 1; b <= cur; ++b) rstart[b] = i;
    if (i == NRES - 1)
      for (int b = cur + 1; b <= NB; ++b) rstart[b] = NRES;
  }
}

// Mega: atoms segsum -> residue masked segsum -> wave-level norm/topk -> hin scatter.
// Blocks [NB, NB+2048): bemb split-K atomic.
__global__ __launch_bounds__(256) void k_mega(
    const float* __restrict__ hctx, const float* __restrict__ pos,
    const float* __restrict__ hres, const float* __restrict__ rpos,
    const int* __restrict__ astart, const int* __restrict__ rstart,
    const float* __restrict__ pcnt, const float* __restrict__ wl,
    const float* __restrict__ inv_sp, const float* __restrict__ emb,
    const float* __restrict__ pnT,
    float* __restrict__ nh, int* __restrict__ knn, float* __restrict__ hin) {
  int blk = blockIdx.x, t = threadIdx.x;
  __shared__ int lst[256];
  __shared__ int cnt;
  __shared__ float cw[VCHUNK];
  __shared__ float sre[HD];
  __shared__ float part[256];
  __shared__ float c[NP];
  __shared__ float wsum[4];
  __shared__ int kk[4];
  __shared__ float scen[3];
  if (blk < NB) {
    int b = blk;
    int lane = t & 63, w = t >> 6;
    // ---- atoms segment sum ----
    int s = astart[b], e = astart[b + 1];
    {
      float a0 = 0.f, a1 = 0.f, a2 = 0.f, a3 = 0.f;
      int a = s;
      for (; a + 3 < e; a += 4) {
        a0 += hctx[(size_t)(a + 0) * HD + t];
        a1 += hctx[(size_t)(a + 1) * HD + t];
        a2 += hctx[(size_t)(a + 2) * HD + t];
        a3 += hctx[(size_t)(a + 3) * HD + t];
      }
      for (; a < e; ++a) a0 += hctx[(size_t)a * HD + t];
      nh[(size_t)b * HD + t] = (a0 + a1) + (a2 + a3);
      if (t < 3) {
        float ps = 0.f;
        for (int aa = s; aa < e; ++aa) ps += pos[aa * 3 + t];
        scen[t] = ps / fmaxf((float)(e - s), 1.0f);
      }
    }
    __syncthreads();
    float c0 = scen[0], c1 = scen[1], c2 = scen[2];
    // ---- residue masked segment sum ----
    int rs = rstart[b], re_ = rstart[b + 1];
    float a0 = 0.f, a1 = 0.f, a2 = 0.f, a3 = 0.f, a4 = 0.f, a5 = 0.f, a6 = 0.f, a7 = 0.f;
    for (int cc = rs; cc < re_; cc += 256) {
      if (!t) cnt = 0;
      __syncthreads();
      int r = cc + t;
      if (r < re_) {
        float dx = rpos[(size_t)r * 9 + 3] - c0;
        float dy = rpos[(size_t)r * 9 + 4] - c1;
        float dz = rpos[(size_t)r * 9 + 5] - c2;
        if (dx * dx + dy * dy + dz * dz < 36.0f) {
          int j = atomicAdd(&cnt, 1);
          lst[j] = r;
        }
      }
      __syncthreads();
      int n = cnt;
      int j = 0;
      for (; j + 7 < n; j += 8) {
        a0 += hres[(size_t)lst[j + 0] * HD + t];
        a1 += hres[(size_t)lst[j + 1] * HD + t];
        a2 += hres[(size_t)lst[j + 2] * HD + t];
        a3 += hres[(size_t)lst[j + 3] * HD + t];
        a4 += hres[(size_t)lst[j + 4] * HD + t];
        a5 += hres[(size_t)lst[j + 5] * HD + t];
        a6 += hres[(size_t)lst[j + 6] * HD + t];
        a7 += hres[(size_t)lst[j + 7] * HD + t];
      }
      for (; j < n; ++j) a0 += hres[(size_t)lst[j] * HD + t];
      __syncthreads();
    }
    float acc = ((a0 + a1) + (a2 + a3)) + ((a4 + a5) + (a6 + a7));
    sre[t] = acc;
    // ---- norm: wave shfl reduce (2 barriers) ----
    float ss = acc * acc;
#pragma unroll
    for (int off = 32; off; off >>= 1) ss += __shfl_xor(ss, off);
    if (!lane) wsum[w] = ss;
    __syncthreads();
    float invn = 1.0f / fmaxf(sqrtf((wsum[0] + wsum[1]) + (wsum[2] + wsum[3])), 1e-12f);
    // ---- cos dot (two halves per prototype) ----
    int p = t & 127, half = t >> 7;
    float d = 0.f;
    int h0 = half * 128;
#pragma unroll 8
    for (int h = h0; h < h0 + 128; ++h) d += sre[h] * pnT[h * NP + p];
    part[t] = d;
    __syncthreads();
    if (t < NP) c[t] = (part[t] + part[t + 128]) * invn;
    __syncthreads();
    // ---- top-4: single-wave butterfly (no barriers inside) ----
    if (t < 64) {
      float v0 = c[t], v1 = c[t + 64];
#pragma unroll
      for (int k = 0; k < 4; ++k) {
        float bv = v0; int bi = t;
        if (v1 > bv) { bv = v1; bi = t + 64; }
#pragma unroll
        for (int off = 32; off; off >>= 1) {
          float ov = __shfl_xor(bv, off);
          int oi = __shfl_xor(bi, off);
          if (ov > bv || (ov == bv && oi < bi)) { bv = ov; bi = oi; }
        }
        if (!t) { knn[b * 4 + k] = bi; kk[k] = bi; }
        if (bi == t) v0 = -INFINITY;
        if (bi == t + 64) v1 = -INFINITY;
      }
    }
    __syncthreads();
#pragma unroll
    for (int k = 0; k < 4; ++k) atomicAdd(&hin[kk[k] * HD + t], sre[t]);
  } else {
    int pc = blk - NB;
    int p = pc >> 4, ch = pc & 15;
    int v0 = ch * VCHUNK;
    float isp = inv_sp[p];
    for (int v = t; v < VCHUNK; v += 256) cw[v] = pcnt[(size_t)p * NV + v0 + v] * wl[v0 + v] * isp;
    __syncthreads();
    float acc = 0.f;
#pragma unroll 8
    for (int v = 0; v < VCHUNK; ++v) acc += cw[v] * emb[(size_t)(v0 + v) * HD + t];
    atomicAdd(&hin[p * HD + t], acc);
  }
}

// hw[p] = (relu(hin[p] @ w1)) @ w2
__global__ __launch_bounds__(256) void k_h1hw(const float* __restrict__ hin,
                                              const float* __restrict__ w1,
                                              const float* __restrict__ w2,
                                              float* __restrict__ hw) {
  int p = blockIdx.x, t = threadIdx.x;
  __shared__ float s[HD], s2[HD];
  s[t] = hin[p * HD + t];
  __syncthreads();
  float a = 0.f;
#pragma unroll 8
  for (int h = 0; h < HD; ++h) a += s[h] * w1[h * HD + t];
  s2[t] = fmaxf(a, 0.f);
  __syncthreads();
  float o = 0.f;
#pragma unroll 8
  for (int h = 0; h < HD; ++h) o += s2[h] * w2[h * HD + t];
  hw[p * HD + t] = o;
}

// Build U = [0.8*nh | 0.7*emb[wid] | 1.5*sum(hw[knn])] pre-split to bf16 hi/lo.
__global__ __launch_bounds__(256) void k_prepU(
    const float* __restrict__ nh, const float* __restrict__ emb,
    const int* __restrict__ wid, const int* __restrict__ knn, const float* __restrict__ hw,
    unsigned short* __restrict__ uH, unsigned short* __restrict__ uL) {
  int b = blockIdx.x, t = threadIdx.x;
  size_t base = (size_t)b * 768;
  float x0 = 0.8f * nh[(size_t)b * HD + t];
  float x1 = 0.7f * emb[(size_t)wid[b] * HD + t];
  int4 kn = ((const int4*)knn)[b];
  float x2 = 1.5f * (hw[kn.x * HD + t] + hw[kn.y * HD + t] +
                     hw[kn.z * HD + t] + hw[kn.w * HD + t]);
  unsigned short h;
  h = f2bf(x0); uH[base + t] = h;       uL[base + t] = f2bf(x0 - bf2f(h));
  h = f2bf(x1); uH[base + 256 + t] = h; uL[base + 256 + t] = f2bf(x1 - bf2f(h));
  h = f2bf(x2); uH[base + 512 + t] = h; uL[base + 512 + t] = f2bf(x2 - bf2f(h));
}

// GEMM1: tb = U @ mw + mb. 64x64 tile, 4 waves, double-buffered LDS, pure-copy staging.
// A = U split [4096][768]; B = mwT split [256][768] ([n][k]).
__global__ __launch_bounds__(256) void k_gemm1(
    const unsigned short* __restrict__ uH, const unsigned short* __restrict__ uL,
    const unsigned short* __restrict__ mwTH, const unsigned short* __restrict__ mwTL,
    const float* __restrict__ mb,
    unsigned short* __restrict__ tbH, unsigned short* __restrict__ tbL) {
  __shared__ __align__(16) unsigned short AH[2][64][40], AL[2][64][40],
                                          BH[2][64][40], BL[2][64][40];
  int tid = threadIdx.x, lane = tid & 63, w = tid >> 6;
  int wm = (w & 1) * 32, wn = (w >> 1) * 32;
  int bm = blockIdx.x * 64, bn = blockIdx.y * 64;
  f32x4 acc[2][2] = {};
  // stage tile kt into buffer bf
#define G1_STAGE(bf, kt)                                                        \
  {                                                                             \
    int e = tid * 8, m = e >> 5, k = e & 31;                                    \
    size_t ia = (size_t)(bm + m) * 768 + (kt) * 32 + k;                         \
    size_t ib = (size_t)(bn + m) * 768 + (kt) * 32 + k;                         \
    *(u16x8*)&AH[bf][m][k] = *(const u16x8*)&uH[ia];                            \
    *(u16x8*)&AL[bf][m][k] = *(const u16x8*)&uL[ia];                            \
    *(u16x8*)&BH[bf][m][k] = *(const u16x8*)&mwTH[ib];                          \
    *(u16x8*)&BL[bf][m][k] = *(const u16x8*)&mwTL[ib];                          \
  }
  G1_STAGE(0, 0);
  __syncthreads();
  for (int kt = 0; kt < 24; ++kt) {
    int cur = kt & 1;
    if (kt + 1 < 24) G1_STAGE(cur ^ 1, kt + 1);
    int r = lane & 15, kb = (lane >> 4) * 8;
    bf16x8 ah[2], al[2], bh[2], bl[2];
#pragma unroll
    for (int i = 0; i < 2; ++i) {
      ah[i] = *(const bf16x8*)&AH[cur][wm + i * 16 + r][kb];
      al[i] = *(const bf16x8*)&AL[cur][wm + i * 16 + r][kb];
      bh[i] = *(const bf16x8*)&BH[cur][wn + i * 16 + r][kb];
      bl[i] = *(const bf16x8*)&BL[cur][wn + i * 16 + r][kb];
    }
#pragma unroll
    for (int i = 0; i < 2; ++i)
#pragma unroll
      for (int j = 0; j < 2; ++j) {
        acc[i][j] = __builtin_amdgcn_mfma_f32_16x16x32_bf16(ah[i], bh[j], acc[i][j], 0, 0, 0);
        acc[i][j] = __builtin_amdgcn_mfma_f32_16x16x32_bf16(ah[i], bl[j], acc[i][j], 0, 0, 0);
        acc[i][j] = __builtin_amdgcn_mfma_f32_16x16x32_bf16(al[i], bh[j], acc[i][j], 0, 0, 0);
      }
    __syncthreads();
  }
  int col0 = lane & 15, row0 = (lane >> 4) * 4;
#pragma unroll
  for (int i = 0; i < 2; ++i)
#pragma unroll
    for (int j = 0; j < 2; ++j) {
      int col = bn + wn + j * 16 + col0;
      float bv = mb[col];
#pragma unroll
      for (int rr = 0; rr < 4; ++rr) {
        int row = bm + wm + i * 16 + row0 + rr;
        float x = acc[i][j][rr] + bv;
        unsigned short h = f2bf(x);
        tbH[(size_t)row * HD + col] = h;
        tbL[(size_t)row * HD + col] = f2bf(x - bf2f(h));
      }
    }
}

// GEMM2: out = tb @ emb^T. 128x128 tile, double-buffered LDS, XCD-swizzled grid.
__global__ __launch_bounds__(256) void k_gemm2(
    const unsigned short* __restrict__ tbH, const unsigned short* __restrict__ tbL,
    const unsigned short* __restrict__ embH, const unsigned short* __restrict__ embL,
    float* __restrict__ out) {
  __shared__ __align__(16) unsigned short AH[2][128][40], AL[2][128][40],
                                          BH[2][128][40], BL[2][128][40];
  int tid = threadIdx.x, lane = tid & 63, w = tid >> 6;
  int wm = (w & 1) * 64, wn = (w >> 1) * 64;
  int orig = blockIdx.x;                       // 512 blocks, 512 % 8 == 0
  int swz = (orig & 7) * 64 + (orig >> 3);     // bijective XCD swizzle
  int bm = (swz & 31) * 128, bn = (swz >> 5) * 128;
  f32x4 acc[4][4] = {};
#define G2_STAGE(bf, kt)                                                        \
  {                                                                             \
    _Pragma("unroll")                                                           \
    for (int cch = 0; cch < 2; ++cch) {                                         \
      int e = (tid + cch * 256) * 8;                                            \
      int m = e >> 5, k = e & 31;                                               \
      size_t ia = (size_t)(bm + m) * HD + (kt) * 32 + k;                        \
      size_t ib = (size_t)(bn + m) * HD + (kt) * 32 + k;                        \
      *(u16x8*)&AH[bf][m][k] = *(const u16x8*)&tbH[ia];                         \
      *(u16x8*)&AL[bf][m][k] = *(const u16x8*)&tbL[ia];                         \
      *(u16x8*)&BH[bf][m][k] = *(const u16x8*)&embH[ib];                        \
      *(u16x8*)&BL[bf][m][k] = *(const u16x8*)&embL[ib];                        \
    }                                                                           \
  }
  G2_STAGE(0, 0);
  __syncthreads();
  for (int kt = 0; kt < 8; ++kt) {
    int cur = kt & 1;
    if (kt + 1 < 8) G2_STAGE(cur ^ 1, kt + 1);
    int r = lane & 15, kb = (lane >> 4) * 8;
    bf16x8 ah[4], al[4], bh[4], bl[4];
#pragma unroll
    for (int i = 0; i < 4; ++i) {
      ah[i] = *(const bf16x8*)&AH[cur][wm + i * 16 + r][kb];
      al[i] = *(const bf16x8*)&AL[cur][wm + i * 16 + r][kb];
      bh[i] = *(const bf16x8*)&BH[cur][wn + i * 16 + r][kb];
      bl[i] = *(const bf16x8*)&BL[cur][wn + i * 16 + r][kb];
    }
#pragma unroll
    for (int i = 0; i < 4; ++i)
#pragma unroll
      for (int j = 0; j < 4; ++j) {
        acc[i][j] = __builtin_amdgcn_mfma_f32_16x16x32_bf16(ah[i], bh[j], acc[i][j], 0, 0, 0);
        acc[i][j] = __builtin_amdgcn_mfma_f32_16x16x32_bf16(ah[i], bl[j], acc[i][j], 0, 0, 0);
        acc[i][j] = __builtin_amdgcn_mfma_f32_16x16x32_bf16(al[i], bh[j], acc[i][j], 0, 0, 0);
      }
    __syncthreads();
  }
  int col0 = lane & 15, row0 = (lane >> 4) * 4;
#pragma unroll
  for (int i = 0; i < 4; ++i)
#pragma unroll
    for (int j = 0; j < 4; ++j) {
      int col = bn + wn + j * 16 + col0;
      if (col <= 2000) {
#pragma unroll
        for (int rr = 0; rr < 4; ++rr) {
          int row = bm + wm + i * 16 + row0 + rr;
          out[(size_t)row * 2001 + col] = acc[i][j][rr];
        }
      }
    }
}

extern "C" void kernel_launch(void* const* d_in, const int* in_sizes, int n_in,
                              void* d_out, int out_size, void* d_ws, size_t ws_size,
                              hipStream_t stream) {
  const float* hctx  = (const float*)d_in[0];
  const float* pos   = (const float*)d_in[1];
  const float* hres  = (const float*)d_in[2];
  const float* rpos  = (const float*)d_in[3];
  const float* emb   = (const float*)d_in[4];
  const float* proto = (const float*)d_in[5];
  const float* pcnt  = (const float*)d_in[6];
  const float* mw    = (const float*)d_in[7];
  const float* mb    = (const float*)d_in[8];
  const float* w1    = (const float*)d_in[9];
  const float* w2    = (const float*)d_in[10];
  const int* wid     = (const int*)d_in[11];
  const int* ab      = (const int*)d_in[12];
  const int* rb      = (const int*)d_in[13];
  float* out = (float*)d_out;

  float* ws     = (float*)d_ws;
  float* nh     = ws;                            // NB*HD
  float* inv_sp = nh + (size_t)NB * HD;          // 128
  float* wl     = inv_sp + 128;                  // 2048 (2000 used)
  float* pnT    = wl + 2048;                     // HD*NP
  float* hin    = pnT + NP * HD;                 // NP*HD
  float* hw     = hin + NP * HD;                 // NP*HD
  int*   knn    = (int*)(hw + NP * HD);          // NB*4 ints
  int*   astart = knn + NB * 4;                  // 4104 ints
  int*   rstart = astart + 4104;                 // 4104 ints
  unsigned short* tbH  = (unsigned short*)(rstart + 4104);  // NB*HD
  unsigned short* tbL  = tbH + (size_t)NB * HD;
  unsigned short* embH = tbL + (size_t)NB * HD;             // 2048*HD
  unsigned short* embL = embH + (size_t)2048 * HD;
  unsigned short* mwTH = embL + (size_t)2048 * HD;          // 768*HD? no: 256 rows x 768 -> 196608
  unsigned short* mwTL = mwTH + (size_t)768 * HD;
  unsigned short* uH   = mwTL + (size_t)768 * HD;           // NB*768
  unsigned short* uL   = uH + (size_t)NB * 768;

  k_init0<<<I_RS, 256, 0, stream>>>(ab, rb, pcnt, proto, emb, mw,
                                    inv_sp, wl, pnT, hin,
                                    embH, embL, mwTH, mwTL, astart, rstart);
  k_mega<<<NB + NP * 16, 256, 0, stream>>>(hctx, pos, hres, rpos, astart, rstart,
                                           pcnt, wl, inv_sp, emb, pnT, nh, knn, hin);
  k_h1hw<<<NP, 256, 0, stream>>>(hin, w1, w2, hw);
  k_prepU<<<NB, 256, 0, stream>>>(nh, emb, wid, knn, hw, uH, uL);
  k_gemm1<<<dim3(NB / 64, 4), 256, 0, stream>>>(uH, uL, mwTH, mwTL, mb, tbH, tbL);
  k_gemm2<<<512, 256, 0, stream>>>(tbH, tbL, embH, embL, out);
}